// Round 11
// baseline (346.290 us; speedup 1.0000x reference)
//
#include <hip/hip_runtime.h>

// ---------------------------------------------------------------------------
// EncoderLayer on MI355X (gfx950). fp32 in/out, bf16 MFMA compute inside.
// B=4 S=2048 D=768 H=12 Dk=64 Dff=2048, M = B*S = 8192 tokens.
//
// Round 17: QKV ported to the 4-phase g4p schedule (proven on Wo/FF2 in r16,
// 2-phase 400 TF -> 4-phase ~550-600 TF). qkv4p_k = g4p_k body + tri-output
// epilogue in the swapped-operand layout (r16->m, qd*4+rr->n): Q/K packed
// bf16x4 row stores; V transposed scalar stores (1/3 of blocks).
// Everything else = r16.
// ---------------------------------------------------------------------------

typedef unsigned short u16;
typedef __bf16 bf16x8 __attribute__((ext_vector_type(8)));
typedef __bf16 bf16x4 __attribute__((ext_vector_type(4)));
typedef unsigned short u16x8 __attribute__((ext_vector_type(8)));
typedef float f32x4 __attribute__((ext_vector_type(4)));

#define D_MODEL 768
#define D_FF    2048
#define NH      12
#define DK      64
#define S_LEN   2048
#define M_TOK   8192

#define QSCALE   0.18033688011112042f   /* 0.125 * log2(e) */
#define MSCALE  -1.4426950408889634e9f  /* -1e9 * log2(e)  */

__device__ __forceinline__ float bf2f(u16 v) {
    union { unsigned u; float f; } c; c.u = ((unsigned)v) << 16; return c.f;
}
__device__ __forceinline__ void st_bf(u16* p, float v) { *(__bf16*)p = (__bf16)v; }

// async global->LDS, 16B/lane; LDS dest must be wave-uniform base + lane*16.
__device__ __forceinline__ void gload_lds16(const void* g, void* l) {
    __builtin_amdgcn_global_load_lds(
        (const __attribute__((address_space(1))) void*)g,
        (__attribute__((address_space(3))) void*)l, 16, 0, 0);
}

// ---------------------------------------------------------------------------
// Fused prep: blocks [0,2304) = 4x 768x768 transposes; [2304,3840) = W1
// (768x2048); [3840,5376) = W2 (2048x768); [5376,11520) = x fp32->bf16.
// ---------------------------------------------------------------------------
__global__ __launch_bounds__(256)
void prep_k(const float* __restrict__ x, const float* __restrict__ Wq,
            const float* __restrict__ Wk, const float* __restrict__ Wv,
            const float* __restrict__ Wo, const float* __restrict__ W1,
            const float* __restrict__ W2, u16* __restrict__ xb,
            u16* __restrict__ WqkvT, u16* __restrict__ WoT,
            u16* __restrict__ W1T, u16* __restrict__ W2T) {
    __shared__ float t[32][33];
    const int id = blockIdx.x, tid = threadIdx.x;
    if (id >= 5376) {               // ---- x convert ----
        const int i = ((id - 5376) * 256 + tid) * 4;
        const float4 v = *(const float4*)(x + i);
        __bf16 o[4] = {(__bf16)v.x, (__bf16)v.y, (__bf16)v.z, (__bf16)v.w};
        *(bf16x4*)(xb + i) = *(bf16x4*)o;
        return;
    }
    const float* in; u16* out; int R, C, bx, by;
    if (id < 2304) {                // ---- Wq/Wk/Wv/Wo 768x768 ----
        const int z = id / 576, r = id % 576;
        in = z == 0 ? Wq : (z == 1 ? Wk : (z == 2 ? Wv : Wo));
        out = z == 3 ? WoT : WqkvT + z * 768 * 768;
        R = 768; C = 768; bx = (r % 24) * 32; by = (r / 24) * 32;
    } else if (id < 3840) {         // ---- W1 [768,2048] -> [2048,768] ----
        const int r = id - 2304;
        in = W1; out = W1T; R = 768; C = 2048;
        bx = (r % 64) * 32; by = (r / 64) * 32;
    } else {                        // ---- W2 [2048,768] -> [768,2048] ----
        const int r = id - 3840;
        in = W2; out = W2T; R = 2048; C = 768;
        bx = (r % 24) * 32; by = (r / 24) * 32;
    }
    const int tx = tid & 31, ty = tid >> 5;
#pragma unroll
    for (int i = 0; i < 32; i += 8)
        t[ty + i][tx] = in[(size_t)(by + ty + i) * C + bx + tx];
    __syncthreads();
#pragma unroll
    for (int i = 0; i < 32; i += 8)
        st_bf(&out[(size_t)(bx + ty + i) * R + by + tx], t[tx][ty + i]);
}

// ---------------------------------------------------------------------------
// QKV 4-phase GEMM: 128x128 tile, 256 thr = 4 waves (2M x 2N), 64KB dbuf
// LDS, swizzled, stages front-loaded, per-iter {ph1 reads+stageA'+16MFMA |
// barrier | ph2 reads+stageB'+16MFMA | vmcnt(0)+barrier}. Grid (64,18).
// Swapped operands: r16 -> m, qd*4+rr -> n (4 consecutive n per lane).
// n0<768: Q*QSCALE -> Qb (packed); <1536: K -> Kb (packed); else V -> Vt
// ([B,H,Dk,S], scalar stores).
// ---------------------------------------------------------------------------
__global__ __launch_bounds__(256, 2)
void qkv4p_k(const u16* __restrict__ A, const u16* __restrict__ Bt,
             const float* __restrict__ bq, const float* __restrict__ bk,
             const float* __restrict__ bv, u16* __restrict__ Qb,
             u16* __restrict__ Kb, u16* __restrict__ Vt) {
    __shared__ __align__(16) u16 AB[2][16384];   // 64 KB
    const int tid = threadIdx.x, lane = tid & 63;
    const int w = tid >> 6;                       // 0..3
    const int wm2 = w >> 1, wn2 = w & 1;          // 2M x 2N
    const int r16 = lane & 15, qd = lane >> 4;
    const int qdx = (qd ^ ((r16 >> 1) & 3)) << 3; // swizzled read slot (u16)
    const int m0 = blockIdx.x * 128, n0 = blockIdx.y * 128;
    const int K = D_MODEL, NT = 12;

    const u16* aS[4]; const u16* bS[4];
#pragma unroll
    for (int l = 0; l < 4; ++l) {
        const int f = l * 256 + tid;
        const int row = (f >> 2) & 127, ks = f >> 9;
        const int e = (((f & 3) ^ ((f >> 3) & 3)) << 3);
        aS[l] = A  + (size_t)(m0 + row) * K + ks * 32 + e;
        bS[l] = Bt + (size_t)(n0 + row) * K + ks * 32 + e;
    }

    // prologue: stage tile 0
#pragma unroll
    for (int l = 0; l < 4; ++l) {
        gload_lds16(aS[l], &AB[0][(l * 256 + tid) * 8]);
        gload_lds16(bS[l], &AB[0][8192 + (l * 256 + tid) * 8]);
    }
    asm volatile("s_waitcnt vmcnt(0)" ::: "memory");
    __builtin_amdgcn_s_barrier();

    f32x4 acc[4][4] = {};
    bf16x8 af[4][2], bfr[4][2];
    const int arow0 = wm2 * 64 + r16;             // + mt*16
    const int brow0 = wn2 * 64 + r16;             // + nt*16

    for (int t = 0; t < NT; ++t) {
        const int cur = t & 1, nxt = cur ^ 1;
        const u16* ab = AB[cur];
        const int ka = (t + 1) * 64;
        const bool more = (t + 1) < NT;

        // ---- phase 1: af 8 + bfr(nt0,1) 4 reads; stage ALL 4 A' -----------
#pragma unroll
        for (int mt = 0; mt < 4; ++mt)
#pragma unroll
            for (int ks = 0; ks < 2; ++ks)
                af[mt][ks] = *(const bf16x8*)&ab[ks * 4096 + (arow0 + mt * 16) * 32 + qdx];
#pragma unroll
        for (int nt = 0; nt < 2; ++nt)
#pragma unroll
            for (int ks = 0; ks < 2; ++ks)
                bfr[nt][ks] = *(const bf16x8*)&ab[8192 + ks * 4096 + (brow0 + nt * 16) * 32 + qdx];
        if (more) {
#pragma unroll
            for (int l = 0; l < 4; ++l)
                gload_lds16(aS[l] + ka, &AB[nxt][(l * 256 + tid) * 8]);
        }
        __builtin_amdgcn_s_setprio(1);
#pragma unroll
        for (int mt = 0; mt < 4; ++mt)
#pragma unroll
            for (int nt = 0; nt < 2; ++nt)
#pragma unroll
                for (int ks = 0; ks < 2; ++ks)
                    acc[mt][nt] = __builtin_amdgcn_mfma_f32_16x16x32_bf16(bfr[nt][ks], af[mt][ks], acc[mt][nt], 0, 0, 0);
        __builtin_amdgcn_s_setprio(0);
        __builtin_amdgcn_s_barrier();

        // ---- phase 2: bfr(nt2,3) 4 reads; stage ALL 4 B' ------------------
#pragma unroll
        for (int nt = 2; nt < 4; ++nt)
#pragma unroll
            for (int ks = 0; ks < 2; ++ks)
                bfr[nt][ks] = *(const bf16x8*)&ab[8192 + ks * 4096 + (brow0 + nt * 16) * 32 + qdx];
        if (more) {
#pragma unroll
            for (int l = 0; l < 4; ++l)
                gload_lds16(bS[l] + ka, &AB[nxt][8192 + (l * 256 + tid) * 8]);
        }
        __builtin_amdgcn_s_setprio(1);
#pragma unroll
        for (int mt = 0; mt < 4; ++mt)
#pragma unroll
            for (int nt = 2; nt < 4; ++nt)
#pragma unroll
                for (int ks = 0; ks < 2; ++ks)
                    acc[mt][nt] = __builtin_amdgcn_mfma_f32_16x16x32_bf16(bfr[nt][ks], af[mt][ks], acc[mt][nt], 0, 0, 0);
        __builtin_amdgcn_s_setprio(0);

        if (more) {
            asm volatile("s_waitcnt vmcnt(0)" ::: "memory");
            __builtin_amdgcn_s_barrier();
        }
    }

    // ---- tri-output epilogue ---------------------------------------------
    const int sel = n0 < 768 ? 0 : (n0 < 1536 ? 1 : 2);
    const float* bias = sel == 0 ? bq : (sel == 1 ? bk : bv);
    const float scale = sel == 0 ? QSCALE : 1.0f;
    const int nbase = n0 - sel * 768;

#pragma unroll
    for (int nt = 0; nt < 4; ++nt) {
        const int nb = nbase + wn2 * 64 + nt * 16 + qd * 4;   // 4 consec cols
        const float4 bvv = *(const float4*)&bias[nb];
        const float b4[4] = {bvv.x, bvv.y, bvv.z, bvv.w};
#pragma unroll
        for (int mi = 0; mi < 4; ++mi) {
            const int m = m0 + wm2 * 64 + mi * 16 + r16;
            if (sel < 2) {
                __bf16 pk[4];
#pragma unroll
                for (int rr = 0; rr < 4; ++rr)
                    pk[rr] = (__bf16)((acc[mi][nt][rr] + b4[rr]) * scale);
                u16* dst = (sel == 0 ? Qb : Kb) + (size_t)m * D_MODEL + nb;
                *(bf16x4*)dst = *(bf16x4*)pk;
            } else {
                const int bb = m >> 11, npb = m & 2047;
#pragma unroll
                for (int rr = 0; rr < 4; ++rr) {
                    const int col = nb + rr, h = col >> 6, d = col & 63;
                    st_bf(&Vt[(((size_t)(bb * NH + h)) * DK + d) * S_LEN + npb],
                          acc[mi][nt][rr] + b4[rr]);
                }
            }
        }
    }
}

// ---------------------------------------------------------------------------
// g4p: 128x128 4-phase GEMM (Wo + FF2). C = A @ Bt^T + bias. 256 thr =
// 4 waves (2M x 2N), per-wave output 64x64. LDS 64KB dbuf, swizzled.
// ---------------------------------------------------------------------------
__global__ __launch_bounds__(256, 2)
void g4p_k(const u16* __restrict__ A, const u16* __restrict__ Bt,
           const float* __restrict__ bias, u16* __restrict__ Cout,
           int N, int K) {
    __shared__ __align__(16) u16 AB[2][16384];   // 64 KB
    const int tid = threadIdx.x, lane = tid & 63;
    const int w = tid >> 6;                       // 0..3
    const int wm2 = w >> 1, wn2 = w & 1;          // 2M x 2N
    const int r16 = lane & 15, qd = lane >> 4;
    const int qdx = (qd ^ ((r16 >> 1) & 3)) << 3; // swizzled read slot (u16)
    const int m0 = blockIdx.x * 128, n0 = blockIdx.y * 128;
    const int NT = K >> 6;

    const u16* aS[4]; const u16* bS[4];
#pragma unroll
    for (int l = 0; l < 4; ++l) {
        const int f = l * 256 + tid;
        const int row = (f >> 2) & 127, ks = f >> 9;
        const int e = (((f & 3) ^ ((f >> 3) & 3)) << 3);
        aS[l] = A  + (size_t)(m0 + row) * K + ks * 32 + e;
        bS[l] = Bt + (size_t)(n0 + row) * K + ks * 32 + e;
    }

    // prologue: stage tile 0
#pragma unroll
    for (int l = 0; l < 4; ++l) {
        gload_lds16(aS[l], &AB[0][(l * 256 + tid) * 8]);
        gload_lds16(bS[l], &AB[0][8192 + (l * 256 + tid) * 8]);
    }
    asm volatile("s_waitcnt vmcnt(0)" ::: "memory");
    __builtin_amdgcn_s_barrier();

    f32x4 acc[4][4] = {};
    bf16x8 af[4][2], bfr[4][2];
    const int arow0 = wm2 * 64 + r16;             // + mt*16
    const int brow0 = wn2 * 64 + r16;             // + nt*16

    for (int t = 0; t < NT; ++t) {
        const int cur = t & 1, nxt = cur ^ 1;
        const u16* ab = AB[cur];
        const int ka = (t + 1) * 64;
        const bool more = (t + 1) < NT;

        // ---- phase 1: af 8 + bfr(nt0,1) 4 reads; stage ALL 4 A' -----------
#pragma unroll
        for (int mt = 0; mt < 4; ++mt)
#pragma unroll
            for (int ks = 0; ks < 2; ++ks)
                af[mt][ks] = *(const bf16x8*)&ab[ks * 4096 + (arow0 + mt * 16) * 32 + qdx];
#pragma unroll
        for (int nt = 0; nt < 2; ++nt)
#pragma unroll
            for (int ks = 0; ks < 2; ++ks)
                bfr[nt][ks] = *(const bf16x8*)&ab[8192 + ks * 4096 + (brow0 + nt * 16) * 32 + qdx];
        if (more) {
#pragma unroll
            for (int l = 0; l < 4; ++l)
                gload_lds16(aS[l] + ka, &AB[nxt][(l * 256 + tid) * 8]);
        }
        __builtin_amdgcn_s_setprio(1);
#pragma unroll
        for (int mt = 0; mt < 4; ++mt)
#pragma unroll
            for (int nt = 0; nt < 2; ++nt)
#pragma unroll
                for (int ks = 0; ks < 2; ++ks)
                    acc[mt][nt] = __builtin_amdgcn_mfma_f32_16x16x32_bf16(bfr[nt][ks], af[mt][ks], acc[mt][nt], 0, 0, 0);
        __builtin_amdgcn_s_setprio(0);
        __builtin_amdgcn_s_barrier();

        // ---- phase 2: bfr(nt2,3) 4 reads; stage ALL 4 B' ------------------
#pragma unroll
        for (int nt = 2; nt < 4; ++nt)
#pragma unroll
            for (int ks = 0; ks < 2; ++ks)
                bfr[nt][ks] = *(const bf16x8*)&ab[8192 + ks * 4096 + (brow0 + nt * 16) * 32 + qdx];
        if (more) {
#pragma unroll
            for (int l = 0; l < 4; ++l)
                gload_lds16(bS[l] + ka, &AB[nxt][8192 + (l * 256 + tid) * 8]);
        }
        __builtin_amdgcn_s_setprio(1);
#pragma unroll
        for (int mt = 0; mt < 4; ++mt)
#pragma unroll
            for (int nt = 2; nt < 4; ++nt)
#pragma unroll
                for (int ks = 0; ks < 2; ++ks)
                    acc[mt][nt] = __builtin_amdgcn_mfma_f32_16x16x32_bf16(bfr[nt][ks], af[mt][ks], acc[mt][nt], 0, 0, 0);
        __builtin_amdgcn_s_setprio(0);

        // ---- iter end: drain stages of t+1, flip --------------------------
        if (more) {
            asm volatile("s_waitcnt vmcnt(0)" ::: "memory");
            __builtin_amdgcn_s_barrier();
        }
    }

    // ---- epilogue: n = n0+wn2*64+nt*16+qd*4+rr, m = m0+wm2*64+mt*16+r16 ---
#pragma unroll
    for (int nt = 0; nt < 4; ++nt) {
        const int nb = n0 + wn2 * 64 + nt * 16 + qd * 4;
        const float4 bv = *(const float4*)&bias[nb];
        const float b4[4] = {bv.x, bv.y, bv.z, bv.w};
#pragma unroll
        for (int mi = 0; mi < 4; ++mi) {
            const int m = m0 + wm2 * 64 + mi * 16 + r16;
            __bf16 pk[4];
#pragma unroll
            for (int rr = 0; rr < 4; ++rr)
                pk[rr] = (__bf16)(acc[mi][nt][rr] + b4[rr]);
            *(bf16x4*)&Cout[(size_t)m * N + nb] = *(bf16x4*)pk;
        }
    }
}

// ---------------------------------------------------------------------------
// FF1: H1 = relu(X1 @ W1 + b1). 256x256 tile, BK=64, 512 thr = 8 waves
// (2M x 4N), 128KB dbuf LDS, XOR-swizzled, stages front-loaded (phases 1-2).
// Grid 32x8 = 256 blocks = 1/CU.
// ---------------------------------------------------------------------------
__global__ __launch_bounds__(512, 2)
void ff1_k(const u16* __restrict__ A, const u16* __restrict__ Bt,
           const float* __restrict__ bias, u16* __restrict__ C) {
    __shared__ __align__(16) u16 AB[2][32768];   // 128 KB
    const int tid = threadIdx.x, lane = tid & 63;
    const int w = tid >> 6;                       // 0..7
    const int wm2 = w >> 2, wn4 = w & 3;          // 2M x 4N
    const int r16 = lane & 15, qd = lane >> 4;
    const int qdx = (qd ^ ((r16 >> 1) & 3)) << 3; // swizzled read slot (u16)
    const int m0 = blockIdx.x * 256, n0 = blockIdx.y * 256;
    const int K = D_MODEL, NT = 12;

    // staging sources: load l -> f = l*512+tid; LDS elem L=f*8 corresponds to
    // (ks=f>>10, row=(f>>2)&255, slot=f&3); source slot pre-swizzled.
    const u16* aS[4]; const u16* bS[4];
#pragma unroll
    for (int l = 0; l < 4; ++l) {
        const int f = l * 512 + tid;
        const int row = (f >> 2) & 255, ks = f >> 10;
        const int e = (((f & 3) ^ ((f >> 3) & 3)) << 3);
        aS[l] = A  + (size_t)(m0 + row) * K + ks * 32 + e;
        bS[l] = Bt + (size_t)(n0 + row) * K + ks * 32 + e;
    }

    // prologue: stage tile 0
#pragma unroll
    for (int l = 0; l < 4; ++l) {
        gload_lds16(aS[l], &AB[0][(l * 512 + tid) * 8]);
        gload_lds16(bS[l], &AB[0][16384 + (l * 512 + tid) * 8]);
    }
    asm volatile("s_waitcnt vmcnt(0)" ::: "memory");
    __builtin_amdgcn_s_barrier();

    f32x4 acc[8][4] = {};
    bf16x8 af[4][2], bfr[4][2];
    const int arow0 = wm2 * 128 + r16;            // + mh*64 + mt*16
    const int brow0 = wn4 * 64 + r16;             // + nt*16

    for (int t = 0; t < NT; ++t) {
        const int cur = t & 1, nxt = cur ^ 1;
        const u16* ab = AB[cur];
        const int ka = (t + 1) * 64;              // k-offset of tile t+1
        const bool more = (t + 1) < NT;

        // ---- phase 1: af(mh=0) 8 + bfr(nt0,1) 4 reads; stage ALL 4 A' -----
#pragma unroll
        for (int mt = 0; mt < 4; ++mt)
#pragma unroll
            for (int ks = 0; ks < 2; ++ks)
                af[mt][ks] = *(const bf16x8*)&ab[ks * 8192 + (arow0 + mt * 16) * 32 + qdx];
#pragma unroll
        for (int nt = 0; nt < 2; ++nt)
#pragma unroll
            for (int ks = 0; ks < 2; ++ks)
                bfr[nt][ks] = *(const bf16x8*)&ab[16384 + ks * 8192 + (brow0 + nt * 16) * 32 + qdx];
        if (more) {
#pragma unroll
            for (int l = 0; l < 4; ++l)
                gload_lds16(aS[l] + ka, &AB[nxt][(l * 512 + tid) * 8]);
        }
        __builtin_amdgcn_s_setprio(1);
#pragma unroll
        for (int mt = 0; mt < 4; ++mt)
#pragma unroll
            for (int nt = 0; nt < 2; ++nt)
#pragma unroll
                for (int ks = 0; ks < 2; ++ks)
                    acc[mt][nt] = __builtin_amdgcn_mfma_f32_16x16x32_bf16(bfr[nt][ks], af[mt][ks], acc[mt][nt], 0, 0, 0);
        __builtin_amdgcn_s_setprio(0);
        __builtin_amdgcn_s_barrier();

        // ---- phase 2: bfr(nt2,3) 4 reads; stage ALL 4 B' ------------------
#pragma unroll
        for (int nt = 2; nt < 4; ++nt)
#pragma unroll
            for (int ks = 0; ks < 2; ++ks)
                bfr[nt][ks] = *(const bf16x8*)&ab[16384 + ks * 8192 + (brow0 + nt * 16) * 32 + qdx];
        if (more) {
#pragma unroll
            for (int l = 0; l < 4; ++l)
                gload_lds16(bS[l] + ka, &AB[nxt][16384 + (l * 512 + tid) * 8]);
        }
        __builtin_amdgcn_s_setprio(1);
#pragma unroll
        for (int mt = 0; mt < 4; ++mt)
#pragma unroll
            for (int nt = 2; nt < 4; ++nt)
#pragma unroll
                for (int ks = 0; ks < 2; ++ks)
                    acc[mt][nt] = __builtin_amdgcn_mfma_f32_16x16x32_bf16(bfr[nt][ks], af[mt][ks], acc[mt][nt], 0, 0, 0);
        __builtin_amdgcn_s_setprio(0);
        __builtin_amdgcn_s_barrier();

        // ---- phase 3: af(mh=1) 8 reads ------------------------------------
#pragma unroll
        for (int mt = 0; mt < 4; ++mt)
#pragma unroll
            for (int ks = 0; ks < 2; ++ks)
                af[mt][ks] = *(const bf16x8*)&ab[ks * 8192 + (arow0 + 64 + mt * 16) * 32 + qdx];
        __builtin_amdgcn_s_setprio(1);
#pragma unroll
        for (int mt = 0; mt < 4; ++mt)
#pragma unroll
            for (int nt = 0; nt < 2; ++nt)
#pragma unroll
                for (int ks = 0; ks < 2; ++ks)
                    acc[4 + mt][nt] = __builtin_amdgcn_mfma_f32_16x16x32_bf16(bfr[nt][ks], af[mt][ks], acc[4 + mt][nt], 0, 0, 0);
        __builtin_amdgcn_s_setprio(0);
        __builtin_amdgcn_s_barrier();

        // ---- phase 4 ------------------------------------------------------
        __builtin_amdgcn_s_setprio(1);
#pragma unroll
        for (int mt = 0; mt < 4; ++mt)
#pragma unroll
            for (int nt = 2; nt < 4; ++nt)
#pragma unroll
                for (int ks = 0; ks < 2; ++ks)
                    acc[4 + mt][nt] = __builtin_amdgcn_mfma_f32_16x16x32_bf16(bfr[nt][ks], af[mt][ks], acc[4 + mt][nt], 0, 0, 0);
        __builtin_amdgcn_s_setprio(0);

        // ---- iter end: drain stages of t+1 (issued 2-3 phases ago), flip --
        if (more) {
            asm volatile("s_waitcnt vmcnt(0)" ::: "memory");
            __builtin_amdgcn_s_barrier();
        }
    }

    // ---- epilogue: n = n0+wn4*64+nt*16+qd*4+rr, m = m0+wm2*128+mh*64+mt*16+r16
#pragma unroll
    for (int nt = 0; nt < 4; ++nt) {
        const int nb = n0 + wn4 * 64 + nt * 16 + qd * 4;
        const float4 bv = *(const float4*)&bias[nb];
        const float b4[4] = {bv.x, bv.y, bv.z, bv.w};
#pragma unroll
        for (int mi = 0; mi < 8; ++mi) {
            const int m = m0 + wm2 * 128 + (mi >> 2) * 64 + (mi & 3) * 16 + r16;
            __bf16 pk[4];
#pragma unroll
            for (int rr = 0; rr < 4; ++rr)
                pk[rr] = (__bf16)fmaxf(acc[mi][nt][rr] + b4[rr], 0.0f);
            *(bf16x4*)&C[(size_t)m * D_FF + nb] = *(bf16x4*)pk;
        }
    }
}

// ---------------------------------------------------------------------------
// Flash attention v9 "key-split" + T5 setprio. Block = 256 thr (4 waves),
// 128 q-rows, kt step 64, grid (16,12,4)=768 -> 3 independent blocks/CU.
// Wave w: qh = w&1 (q-rows qh*64..+63), kh = w>>1 (keys kh*32..+31 per tile).
// Max-free softmax => disjoint-key partials merge by ADDITION after kt loop.
// Layouts: Q,K [B,S,H,Dk]; Vt [B,H,Dk,S]; mask fp32 [B,S]; out [B,S,H*Dk].
// ---------------------------------------------------------------------------
#define TS 72   // LDS row stride (u16): 144 B, 16B-aligned, bank-spreading

__global__ __launch_bounds__(256, 3)
void attn_k(const u16* __restrict__ Qg, const u16* __restrict__ Kg,
            const u16* __restrict__ Vtg, const float* __restrict__ maskg,
            u16* __restrict__ Og) {
    const int tid = threadIdx.x, lane = tid & 63, w = tid >> 6;
    const int qh = w & 1, kh = w >> 1;
    const int r16 = lane & 15, qd = lane >> 4;
    const int q0 = blockIdx.x * 128;
    const int h = blockIdx.y, b = blockIdx.z;

    // one block so the O-merge buffer can overlay the whole tile space
    __shared__ __align__(16) u16 sm[(64 + 64 + 128) * TS];   // 36.9 KB
    u16* Ks  = sm;                  // [64 keys][64 feat]
    u16* Vts = sm + 64 * TS;        // [64 d][64 keys]
    u16* Ps  = sm + 128 * TS;       // [128 q][64 keys]

    // ---- Q fragments in registers (wave's 64 q-rows; same every kt) -------
    bf16x8 qa[4][2];
#pragma unroll
    for (int mt = 0; mt < 4; ++mt)
#pragma unroll
        for (int ks = 0; ks < 2; ++ks)
            qa[mt][ks] = *(const bf16x8*)(Qg +
                ((size_t)((b * S_LEN + q0 + qh * 64 + mt * 16 + r16) * NH + h)) * DK +
                ks * 32 + qd * 8);

    // ---- staging: 256 threads cover each 64x64 tile in 2 strips -----------
    const int srow = tid >> 3, sc = (tid & 7) << 3;
    const u16* vsrc = Vtg + (((size_t)(b * NH + h)) * DK) * S_LEN;   // [d][s]
    u16x8 kreg[2], vreg[2];
#pragma unroll
    for (int it = 0; it < 2; ++it) {
        const int row = srow + it * 32;
        kreg[it] = *(const u16x8*)(Kg + ((size_t)((b * S_LEN + row) * NH + h)) * DK + sc);
        vreg[it] = *(const u16x8*)(vsrc + (size_t)row * S_LEN + sc);
    }

    float l_i[4] = {0.0f, 0.0f, 0.0f, 0.0f};
    f32x4 Oacc[4][4] = {};

    for (int kt = 0; kt < S_LEN / 64; ++kt) {
        const int ks0 = kt * 64;

        // ---- commit prefetched K/Vt tiles to LDS --------------------------
#pragma unroll
        for (int it = 0; it < 2; ++it) {
            const int row = srow + it * 32;
            *(u16x8*)&Ks[row * TS + sc]  = kreg[it];
            *(u16x8*)&Vts[row * TS + sc] = vreg[it];
        }

        // ---- pre-scaled mask, this wave's 32 keys (key = kh*32+nt*16+qd*4+rr)
        float4 mrow[2];
#pragma unroll
        for (int nt = 0; nt < 2; ++nt) {
            const float4 mm = ((const float4*)(maskg + (size_t)b * S_LEN + ks0))[kh * 8 + nt * 4 + qd];
            mrow[nt].x = mm.x * MSCALE; mrow[nt].y = mm.y * MSCALE;
            mrow[nt].z = mm.z * MSCALE; mrow[nt].w = mm.w * MSCALE;
        }
        __syncthreads();

        // ---- S^T = K @ Q^T + mask (mask as acc init); keys kh*32..+31 -----
        f32x4 sa[4][2];
#pragma unroll
        for (int mt = 0; mt < 4; ++mt)
#pragma unroll
            for (int nt = 0; nt < 2; ++nt) {
                sa[mt][nt][0] = mrow[nt].x; sa[mt][nt][1] = mrow[nt].y;
                sa[mt][nt][2] = mrow[nt].z; sa[mt][nt][3] = mrow[nt].w;
            }
#pragma unroll
        for (int ks = 0; ks < 2; ++ks) {
            bf16x8 kb[2];
#pragma unroll
            for (int nt = 0; nt < 2; ++nt)
                kb[nt] = *(const bf16x8*)&Ks[(kh * 32 + nt * 16 + r16) * TS + ks * 32 + qd * 8];
            __builtin_amdgcn_s_setprio(1);
#pragma unroll
            for (int mt = 0; mt < 4; ++mt)
#pragma unroll
                for (int nt = 0; nt < 2; ++nt)
                    sa[mt][nt] = __builtin_amdgcn_mfma_f32_16x16x32_bf16(kb[nt], qa[mt][ks], sa[mt][nt], 0, 0, 0);
            __builtin_amdgcn_s_setprio(0);
        }

        // ---- max-free softmax partial: p = exp2(s), l += sum (32 keys) ----
#pragma unroll
        for (int mt = 0; mt < 4; ++mt) {
            float rsum = 0.0f;
#pragma unroll
            for (int nt = 0; nt < 2; ++nt) {
                sa[mt][nt][0] = __builtin_amdgcn_exp2f(sa[mt][nt][0]);
                sa[mt][nt][1] = __builtin_amdgcn_exp2f(sa[mt][nt][1]);
                sa[mt][nt][2] = __builtin_amdgcn_exp2f(sa[mt][nt][2]);
                sa[mt][nt][3] = __builtin_amdgcn_exp2f(sa[mt][nt][3]);
                rsum += sa[mt][nt][0] + sa[mt][nt][1] + sa[mt][nt][2] + sa[mt][nt][3];
            }
            rsum += __shfl_xor(rsum, 16);
            rsum += __shfl_xor(rsum, 32);
            l_i[mt] += rsum;   // uniform across qd for fixed r16 (q = mt*16+r16)
        }

        // ---- P -> Ps [q][key], wave-private 64x32 block -------------------
#pragma unroll
        for (int mt = 0; mt < 4; ++mt)
#pragma unroll
            for (int nt = 0; nt < 2; ++nt) {
                __bf16 pk[4];
#pragma unroll
                for (int rr = 0; rr < 4; ++rr) pk[rr] = (__bf16)sa[mt][nt][rr];
                *(bf16x4*)&Ps[(qh * 64 + mt * 16 + r16) * TS + kh * 32 + nt * 16 + qd * 4] = *(bf16x4*)pk;
            }

        // ---- issue next tile's global loads (sa dead; caps VGPR peak) -----
        if (kt + 1 < S_LEN / 64) {
            const int ns0 = ks0 + 64;
#pragma unroll
            for (int it = 0; it < 2; ++it) {
                const int row = srow + it * 32;
                kreg[it] = *(const u16x8*)(Kg + ((size_t)((b * S_LEN + ns0 + row) * NH + h)) * DK + sc);
                vreg[it] = *(const u16x8*)(vsrc + (size_t)row * S_LEN + ns0 + sc);
            }
        }

        // ---- O += P @ V over this wave's 32 keys --------------------------
        {
            bf16x8 pa[4], vb[4];
#pragma unroll
            for (int mt = 0; mt < 4; ++mt)
                pa[mt] = *(const bf16x8*)&Ps[(qh * 64 + mt * 16 + r16) * TS + kh * 32 + qd * 8];
#pragma unroll
            for (int vt = 0; vt < 4; ++vt)
                vb[vt] = *(const bf16x8*)&Vts[(vt * 16 + r16) * TS + kh * 32 + qd * 8];
            __builtin_amdgcn_s_setprio(1);
#pragma unroll
            for (int mt = 0; mt < 4; ++mt)
#pragma unroll
                for (int vt = 0; vt < 4; ++vt)
                    Oacc[mt][vt] = __builtin_amdgcn_mfma_f32_16x16x32_bf16(pa[mt], vb[vt], Oacc[mt][vt], 0, 0, 0);
            __builtin_amdgcn_s_setprio(0);
        }
        __syncthreads();   // all waves done with Ks/Vts/Ps before next commit
    }

    // ---- merge kh partials (addition; max-free softmax) -------------------
    __syncthreads();                       // tile space dead, safe to overlay
    float* mb  = (float*)sm;               // [128 q][64 d] fp32 = 32 KB
    float* lsm = mb + 128 * 64;            // [2 qh][4 mt][16 r16] = 512 B
    if (kh == 0) {
#pragma unroll
        for (int mt = 0; mt < 4; ++mt) {
            if (qd == 0) lsm[(qh * 4 + mt) * 16 + r16] = l_i[mt];
#pragma unroll
            for (int vt = 0; vt < 4; ++vt)
#pragma unroll
                for (int rr = 0; rr < 4; ++rr)
                    mb[(qh * 64 + mt * 16 + qd * 4 + rr) * 64 + vt * 16 + r16] = Oacc[mt][vt][rr];
        }
    }
    __syncthreads();
    if (kh == 1) {
#pragma unroll
        for (int mt = 0; mt < 4; ++mt) {
            const float linv = 1.0f / (l_i[mt] + lsm[(qh * 4 + mt) * 16 + r16]);
#pragma unroll
            for (int rr = 0; rr < 4; ++rr) {
                const float lr = __shfl(linv, qd * 4 + rr);
                const int qrow = q0 + qh * 64 + mt * 16 + qd * 4 + rr;
#pragma unroll
                for (int vt = 0; vt < 4; ++vt) {
                    const float o = Oacc[mt][vt][rr] +
                        mb[(qh * 64 + mt * 16 + qd * 4 + rr) * 64 + vt * 16 + r16];
                    st_bf(&Og[((size_t)((b * S_LEN + qrow) * NH + h)) * DK + vt * 16 + r16],
                          o * lr);
                }
            }
        }
    }
}

// ---------------------------------------------------------------------------
// Residual + LayerNorm over D=768. Inputs bf16 x + bf16 y; fp32 math.
// ---------------------------------------------------------------------------
__global__ __launch_bounds__(256, 4)
void resln_k(const u16* __restrict__ xb, const u16* __restrict__ yb,
             const float* __restrict__ gamma, const float* __restrict__ beta,
             u16* __restrict__ outb, float* __restrict__ outf) {
    const int row = blockIdx.x, tid = threadIdx.x;
    const int lane = tid & 63, w = tid >> 6;
    __shared__ float redS[4], redS2[4];
    const size_t base = (size_t)row * D_MODEL;
    float h[3], s = 0.0f, s2 = 0.0f;
#pragma unroll
    for (int i = 0; i < 3; ++i) {
        const int c = i * 256 + tid;
        const float v = bf2f(xb[base + c]) + bf2f(yb[base + c]);
        h[i] = v; s += v; s2 += v * v;
    }
#pragma unroll
    for (int off = 32; off >= 1; off >>= 1) { s += __shfl_xor(s, off); s2 += __shfl_xor(s2, off); }
    if (lane == 0) { redS[w] = s; redS2[w] = s2; }
    __syncthreads();
    s  = redS[0] + redS[1] + redS[2] + redS[3];
    s2 = redS2[0] + redS2[1] + redS2[2] + redS2[3];
    const float mu  = s * (1.0f / D_MODEL);
    const float var = s2 * (1.0f / D_MODEL) - mu * mu;
    const float rstd = rsqrtf(var + 1e-3f);
#pragma unroll
    for (int i = 0; i < 3; ++i) {
        const int c = i * 256 + tid;
        const float o = (h[i] - mu) * rstd * gamma[c] + beta[c];
        if (outb) st_bf(&outb[base + c], o);
        if (outf) outf[base + c] = o;
    }
}

// ---------------------------------------------------------------------------
extern "C" void kernel_launch(void* const* d_in, const int* in_sizes, int n_in,
                              void* d_out, int out_size, void* d_ws, size_t ws_size,
                              hipStream_t stream) {
    (void)in_sizes; (void)n_in; (void)out_size; (void)ws_size;
    const float* x    = (const float*)d_in[0];
    const float* mask = (const float*)d_in[1];
    const float* Wq = (const float*)d_in[2];  const float* bq  = (const float*)d_in[3];
    const float* Wk = (const float*)d_in[4];  const float* bk  = (const float*)d_in[5];
    const float* Wv = (const float*)d_in[6];  const float* bv  = (const float*)d_in[7];
    const float* Wo = (const float*)d_in[8];  const float* bo  = (const float*)d_in[9];
    const float* W1 = (const float*)d_in[10]; const float* b1  = (const float*)d_in[11];
    const float* W2 = (const float*)d_in[12]; const float* b2  = (const float*)d_in[13];
    const float* g1 = (const float*)d_in[14]; const float* be1 = (const float*)d_in[15];
    const float* g2 = (const float*)d_in[16]; const float* be2 = (const float*)d_in[17];

    char* ws = (char*)d_ws;
    u16* xb     = (u16*)(ws + 0);            // 12,582,912
    u16* WqkvT  = (u16*)(ws + 12582912);     //  3,538,944
    u16* WoT    = (u16*)(ws + 16121856);     //  1,179,648
    u16* W1T    = (u16*)(ws + 17301504);     //  3,145,728
    u16* W2T    = (u16*)(ws + 20447232);     //  3,145,728
    u16* Qb     = (u16*)(ws + 23592960);     // 12,582,912
    u16* Kb     = (u16*)(ws + 36175872);     // 12,582,912
    u16* Vtg    = (u16*)(ws + 48758784);     // 12,582,912 [B,H,Dk,S]
    u16* Ab     = (u16*)(ws + 61341696);     // 12,582,912
    u16* Yb     = (u16*)(ws + 73924608);     // 12,582,912
    u16* X1b    = (u16*)(ws + 86507520);     // 12,582,912 (end ~99 MB)
    u16* H1b    = (u16*)(ws + 23592960);     // reuse Qb/Kb/Vtg (dead after attn)
    u16* Y2b    = (u16*)(ws + 73924608);     // reuse Yb (dead after LN1)

    const dim3 blk(256);

    // 0. fused prep: x->bf16 + all 6 weight transposes (one dispatch)
    prep_k<<<dim3(11520), blk, 0, stream>>>(x, Wq, Wk, Wv, Wo, W1, W2,
                                            xb, WqkvT, WoT, W1T, W2T);

    // 1. fused QKV projection: 128^2 4-phase (1152 blocks, 2/CU resident)
    qkv4p_k<<<dim3(64, 18), blk, 0, stream>>>(xb, WqkvT, bq, bk, bv, Qb, Kb, Vtg);

    // 2. flash attention v9 (key-split waves + setprio)
    attn_k<<<dim3(16, NH, 4), blk, 0, stream>>>(Qb, Kb, Vtg, mask, Ab);

    // 3. output projection: 128^2 4-phase (384 blocks, 2/CU resident)
    g4p_k<<<dim3(64, 6), blk, 0, stream>>>(Ab, WoT, bo, Yb, D_MODEL, D_MODEL);

    // 4. LN1: x1 = LN(x + Y) -> bf16
    resln_k<<<dim3(M_TOK), blk, 0, stream>>>(xb, Yb, g1, be1, X1b, nullptr);

    // 5. FF1: H1 = relu(x1@W1 + b1), 256^2 4-phase (front-loaded stages)
    ff1_k<<<dim3(32, 8), dim3(512), 0, stream>>>(X1b, W1T, b1, H1b);

    // 6. FF2: 128^2 4-phase (384 blocks, NT=32)
    g4p_k<<<dim3(64, 6), blk, 0, stream>>>(H1b, W2T, b2, Y2b, D_MODEL, D_FF);

    // 7. LN2: out = LN(x1 + Y2) fp32 -> d_out
    resln_k<<<dim3(M_TOK), blk, 0, stream>>>(X1b, Y2b, g2, be2, nullptr, (float*)d_out);
}

// Round 12
// 333.167 us; speedup vs baseline: 1.0394x; 1.0394x over previous
//
#include <hip/hip_runtime.h>

// ---------------------------------------------------------------------------
// EncoderLayer on MI355X (gfx950). fp32 in/out, bf16 MFMA compute inside.
// B=4 S=2048 D=768 H=12 Dk=64 Dff=2048, M = B*S = 8192 tokens.
//
// Round 18: r17's QKV regression was the swapped-operand epilogue (V became
// a 2B-scalar scatter at 4KB stride). Fix: un-swap (mfma(af,bfr)) so
// rr indexes m=s again, restoring the proven packed-V / scalar-QK epilogue
// from the 2-phase kernel, while keeping the 4-phase body.
// Everything else = r16/r17 (g4p Wo+FF2, ff1 256^2, attn v9+T5).
// ---------------------------------------------------------------------------

typedef unsigned short u16;
typedef __bf16 bf16x8 __attribute__((ext_vector_type(8)));
typedef __bf16 bf16x4 __attribute__((ext_vector_type(4)));
typedef unsigned short u16x8 __attribute__((ext_vector_type(8)));
typedef float f32x4 __attribute__((ext_vector_type(4)));

#define D_MODEL 768
#define D_FF    2048
#define NH      12
#define DK      64
#define S_LEN   2048
#define M_TOK   8192

#define QSCALE   0.18033688011112042f   /* 0.125 * log2(e) */
#define MSCALE  -1.4426950408889634e9f  /* -1e9 * log2(e)  */

__device__ __forceinline__ float bf2f(u16 v) {
    union { unsigned u; float f; } c; c.u = ((unsigned)v) << 16; return c.f;
}
__device__ __forceinline__ void st_bf(u16* p, float v) { *(__bf16*)p = (__bf16)v; }

// async global->LDS, 16B/lane; LDS dest must be wave-uniform base + lane*16.
__device__ __forceinline__ void gload_lds16(const void* g, void* l) {
    __builtin_amdgcn_global_load_lds(
        (const __attribute__((address_space(1))) void*)g,
        (__attribute__((address_space(3))) void*)l, 16, 0, 0);
}

// ---------------------------------------------------------------------------
// Fused prep: blocks [0,2304) = 4x 768x768 transposes; [2304,3840) = W1
// (768x2048); [3840,5376) = W2 (2048x768); [5376,11520) = x fp32->bf16.
// ---------------------------------------------------------------------------
__global__ __launch_bounds__(256)
void prep_k(const float* __restrict__ x, const float* __restrict__ Wq,
            const float* __restrict__ Wk, const float* __restrict__ Wv,
            const float* __restrict__ Wo, const float* __restrict__ W1,
            const float* __restrict__ W2, u16* __restrict__ xb,
            u16* __restrict__ WqkvT, u16* __restrict__ WoT,
            u16* __restrict__ W1T, u16* __restrict__ W2T) {
    __shared__ float t[32][33];
    const int id = blockIdx.x, tid = threadIdx.x;
    if (id >= 5376) {               // ---- x convert ----
        const int i = ((id - 5376) * 256 + tid) * 4;
        const float4 v = *(const float4*)(x + i);
        __bf16 o[4] = {(__bf16)v.x, (__bf16)v.y, (__bf16)v.z, (__bf16)v.w};
        *(bf16x4*)(xb + i) = *(bf16x4*)o;
        return;
    }
    const float* in; u16* out; int R, C, bx, by;
    if (id < 2304) {                // ---- Wq/Wk/Wv/Wo 768x768 ----
        const int z = id / 576, r = id % 576;
        in = z == 0 ? Wq : (z == 1 ? Wk : (z == 2 ? Wv : Wo));
        out = z == 3 ? WoT : WqkvT + z * 768 * 768;
        R = 768; C = 768; bx = (r % 24) * 32; by = (r / 24) * 32;
    } else if (id < 3840) {         // ---- W1 [768,2048] -> [2048,768] ----
        const int r = id - 2304;
        in = W1; out = W1T; R = 768; C = 2048;
        bx = (r % 64) * 32; by = (r / 64) * 32;
    } else {                        // ---- W2 [2048,768] -> [768,2048] ----
        const int r = id - 3840;
        in = W2; out = W2T; R = 2048; C = 768;
        bx = (r % 24) * 32; by = (r / 24) * 32;
    }
    const int tx = tid & 31, ty = tid >> 5;
#pragma unroll
    for (int i = 0; i < 32; i += 8)
        t[ty + i][tx] = in[(size_t)(by + ty + i) * C + bx + tx];
    __syncthreads();
#pragma unroll
    for (int i = 0; i < 32; i += 8)
        st_bf(&out[(size_t)(bx + ty + i) * R + by + tx], t[tx][ty + i]);
}

// ---------------------------------------------------------------------------
// QKV 4-phase GEMM: 128x128 tile, 256 thr = 4 waves (2M x 2N), 64KB dbuf
// LDS, swizzled, stages front-loaded. Standard operand order (mfma(af,bfr)):
// col=r16 -> n, row=qd*4+rr -> m (=s), enabling the proven epilogue:
// V packs 4 consecutive s into bf16x4; Q/K scalar row stores.
// n0<768: Q*QSCALE -> Qb; <1536: K -> Kb; else V -> Vt [B,H,Dk,S].
// ---------------------------------------------------------------------------
__global__ __launch_bounds__(256, 2)
void qkv4p_k(const u16* __restrict__ A, const u16* __restrict__ Bt,
             const float* __restrict__ bq, const float* __restrict__ bk,
             const float* __restrict__ bv, u16* __restrict__ Qb,
             u16* __restrict__ Kb, u16* __restrict__ Vt) {
    __shared__ __align__(16) u16 AB[2][16384];   // 64 KB
    const int tid = threadIdx.x, lane = tid & 63;
    const int w = tid >> 6;                       // 0..3
    const int wm2 = w >> 1, wn2 = w & 1;          // 2M x 2N
    const int r16 = lane & 15, qd = lane >> 4;
    const int qdx = (qd ^ ((r16 >> 1) & 3)) << 3; // swizzled read slot (u16)
    const int m0 = blockIdx.x * 128, n0 = blockIdx.y * 128;
    const int K = D_MODEL, NT = 12;

    const u16* aS[4]; const u16* bS[4];
#pragma unroll
    for (int l = 0; l < 4; ++l) {
        const int f = l * 256 + tid;
        const int row = (f >> 2) & 127, ks = f >> 9;
        const int e = (((f & 3) ^ ((f >> 3) & 3)) << 3);
        aS[l] = A  + (size_t)(m0 + row) * K + ks * 32 + e;
        bS[l] = Bt + (size_t)(n0 + row) * K + ks * 32 + e;
    }

    // prologue: stage tile 0
#pragma unroll
    for (int l = 0; l < 4; ++l) {
        gload_lds16(aS[l], &AB[0][(l * 256 + tid) * 8]);
        gload_lds16(bS[l], &AB[0][8192 + (l * 256 + tid) * 8]);
    }
    asm volatile("s_waitcnt vmcnt(0)" ::: "memory");
    __builtin_amdgcn_s_barrier();

    f32x4 acc[4][4] = {};
    bf16x8 af[4][2], bfr[4][2];
    const int arow0 = wm2 * 64 + r16;             // + mt*16
    const int brow0 = wn2 * 64 + r16;             // + nt*16

    for (int t = 0; t < NT; ++t) {
        const int cur = t & 1, nxt = cur ^ 1;
        const u16* ab = AB[cur];
        const int ka = (t + 1) * 64;
        const bool more = (t + 1) < NT;

        // ---- phase 1: af 8 + bfr(nt0,1) 4 reads; stage ALL 4 A' -----------
#pragma unroll
        for (int mt = 0; mt < 4; ++mt)
#pragma unroll
            for (int ks = 0; ks < 2; ++ks)
                af[mt][ks] = *(const bf16x8*)&ab[ks * 4096 + (arow0 + mt * 16) * 32 + qdx];
#pragma unroll
        for (int nt = 0; nt < 2; ++nt)
#pragma unroll
            for (int ks = 0; ks < 2; ++ks)
                bfr[nt][ks] = *(const bf16x8*)&ab[8192 + ks * 4096 + (brow0 + nt * 16) * 32 + qdx];
        if (more) {
#pragma unroll
            for (int l = 0; l < 4; ++l)
                gload_lds16(aS[l] + ka, &AB[nxt][(l * 256 + tid) * 8]);
        }
        __builtin_amdgcn_s_setprio(1);
#pragma unroll
        for (int mt = 0; mt < 4; ++mt)
#pragma unroll
            for (int nt = 0; nt < 2; ++nt)
#pragma unroll
                for (int ks = 0; ks < 2; ++ks)
                    acc[mt][nt] = __builtin_amdgcn_mfma_f32_16x16x32_bf16(af[mt][ks], bfr[nt][ks], acc[mt][nt], 0, 0, 0);
        __builtin_amdgcn_s_setprio(0);
        __builtin_amdgcn_s_barrier();

        // ---- phase 2: bfr(nt2,3) 4 reads; stage ALL 4 B' ------------------
#pragma unroll
        for (int nt = 2; nt < 4; ++nt)
#pragma unroll
            for (int ks = 0; ks < 2; ++ks)
                bfr[nt][ks] = *(const bf16x8*)&ab[8192 + ks * 4096 + (brow0 + nt * 16) * 32 + qdx];
        if (more) {
#pragma unroll
            for (int l = 0; l < 4; ++l)
                gload_lds16(bS[l] + ka, &AB[nxt][8192 + (l * 256 + tid) * 8]);
        }
        __builtin_amdgcn_s_setprio(1);
#pragma unroll
        for (int mt = 0; mt < 4; ++mt)
#pragma unroll
            for (int nt = 2; nt < 4; ++nt)
#pragma unroll
                for (int ks = 0; ks < 2; ++ks)
                    acc[mt][nt] = __builtin_amdgcn_mfma_f32_16x16x32_bf16(af[mt][ks], bfr[nt][ks], acc[mt][nt], 0, 0, 0);
        __builtin_amdgcn_s_setprio(0);

        if (more) {
            asm volatile("s_waitcnt vmcnt(0)" ::: "memory");
            __builtin_amdgcn_s_barrier();
        }
    }

    // ---- tri-output epilogue (proven layout: col=r16->n, row=qd*4+rr->m) --
    const int sel = n0 < 768 ? 0 : (n0 < 1536 ? 1 : 2);
    const float* bias = sel == 0 ? bq : (sel == 1 ? bk : bv);
    const float scale = sel == 0 ? QSCALE : 1.0f;
    const int nbase = n0 - sel * 768;

#pragma unroll
    for (int nt = 0; nt < 4; ++nt) {
        const int ncol = nbase + wn2 * 64 + nt * 16 + r16;
        const float bvv = bias[ncol];
#pragma unroll
        for (int mi = 0; mi < 4; ++mi) {
            if (sel == 2) {
                // V: pack 4 consecutive s-positions into one b64 store
                const int h = ncol >> 6, d = ncol & 63;
                const int mb = m0 + wm2 * 64 + mi * 16 + qd * 4;
                const int bb = mb >> 11, npb = mb & 2047;
                __bf16 pk[4];
#pragma unroll
                for (int rr = 0; rr < 4; ++rr) pk[rr] = (__bf16)(acc[mi][nt][rr] + bvv);
                *(bf16x4*)&Vt[(((size_t)(bb * NH + h)) * DK + d) * S_LEN + npb] = *(bf16x4*)pk;
            } else {
#pragma unroll
                for (int rr = 0; rr < 4; ++rr) {
                    const int m = m0 + wm2 * 64 + mi * 16 + qd * 4 + rr;
                    const float v = (acc[mi][nt][rr] + bvv) * scale;
                    if (sel == 0) st_bf(&Qb[(size_t)m * D_MODEL + ncol], v);
                    else          st_bf(&Kb[(size_t)m * D_MODEL + ncol], v);
                }
            }
        }
    }
}

// ---------------------------------------------------------------------------
// g4p: 128x128 4-phase GEMM (Wo + FF2). C = A @ Bt^T + bias. 256 thr =
// 4 waves (2M x 2N), per-wave output 64x64. LDS 64KB dbuf, swizzled.
// ---------------------------------------------------------------------------
__global__ __launch_bounds__(256, 2)
void g4p_k(const u16* __restrict__ A, const u16* __restrict__ Bt,
           const float* __restrict__ bias, u16* __restrict__ Cout,
           int N, int K) {
    __shared__ __align__(16) u16 AB[2][16384];   // 64 KB
    const int tid = threadIdx.x, lane = tid & 63;
    const int w = tid >> 6;                       // 0..3
    const int wm2 = w >> 1, wn2 = w & 1;          // 2M x 2N
    const int r16 = lane & 15, qd = lane >> 4;
    const int qdx = (qd ^ ((r16 >> 1) & 3)) << 3; // swizzled read slot (u16)
    const int m0 = blockIdx.x * 128, n0 = blockIdx.y * 128;
    const int NT = K >> 6;

    const u16* aS[4]; const u16* bS[4];
#pragma unroll
    for (int l = 0; l < 4; ++l) {
        const int f = l * 256 + tid;
        const int row = (f >> 2) & 127, ks = f >> 9;
        const int e = (((f & 3) ^ ((f >> 3) & 3)) << 3);
        aS[l] = A  + (size_t)(m0 + row) * K + ks * 32 + e;
        bS[l] = Bt + (size_t)(n0 + row) * K + ks * 32 + e;
    }

    // prologue: stage tile 0
#pragma unroll
    for (int l = 0; l < 4; ++l) {
        gload_lds16(aS[l], &AB[0][(l * 256 + tid) * 8]);
        gload_lds16(bS[l], &AB[0][8192 + (l * 256 + tid) * 8]);
    }
    asm volatile("s_waitcnt vmcnt(0)" ::: "memory");
    __builtin_amdgcn_s_barrier();

    f32x4 acc[4][4] = {};
    bf16x8 af[4][2], bfr[4][2];
    const int arow0 = wm2 * 64 + r16;             // + mt*16
    const int brow0 = wn2 * 64 + r16;             // + nt*16

    for (int t = 0; t < NT; ++t) {
        const int cur = t & 1, nxt = cur ^ 1;
        const u16* ab = AB[cur];
        const int ka = (t + 1) * 64;
        const bool more = (t + 1) < NT;

        // ---- phase 1: af 8 + bfr(nt0,1) 4 reads; stage ALL 4 A' -----------
#pragma unroll
        for (int mt = 0; mt < 4; ++mt)
#pragma unroll
            for (int ks = 0; ks < 2; ++ks)
                af[mt][ks] = *(const bf16x8*)&ab[ks * 4096 + (arow0 + mt * 16) * 32 + qdx];
#pragma unroll
        for (int nt = 0; nt < 2; ++nt)
#pragma unroll
            for (int ks = 0; ks < 2; ++ks)
                bfr[nt][ks] = *(const bf16x8*)&ab[8192 + ks * 4096 + (brow0 + nt * 16) * 32 + qdx];
        if (more) {
#pragma unroll
            for (int l = 0; l < 4; ++l)
                gload_lds16(aS[l] + ka, &AB[nxt][(l * 256 + tid) * 8]);
        }
        __builtin_amdgcn_s_setprio(1);
#pragma unroll
        for (int mt = 0; mt < 4; ++mt)
#pragma unroll
            for (int nt = 0; nt < 2; ++nt)
#pragma unroll
                for (int ks = 0; ks < 2; ++ks)
                    acc[mt][nt] = __builtin_amdgcn_mfma_f32_16x16x32_bf16(bfr[nt][ks], af[mt][ks], acc[mt][nt], 0, 0, 0);
        __builtin_amdgcn_s_setprio(0);
        __builtin_amdgcn_s_barrier();

        // ---- phase 2: bfr(nt2,3) 4 reads; stage ALL 4 B' ------------------
#pragma unroll
        for (int nt = 2; nt < 4; ++nt)
#pragma unroll
            for (int ks = 0; ks < 2; ++ks)
                bfr[nt][ks] = *(const bf16x8*)&ab[8192 + ks * 4096 + (brow0 + nt * 16) * 32 + qdx];
        if (more) {
#pragma unroll
            for (int l = 0; l < 4; ++l)
                gload_lds16(bS[l] + ka, &AB[nxt][8192 + (l * 256 + tid) * 8]);
        }
        __builtin_amdgcn_s_setprio(1);
#pragma unroll
        for (int mt = 0; mt < 4; ++mt)
#pragma unroll
            for (int nt = 2; nt < 4; ++nt)
#pragma unroll
                for (int ks = 0; ks < 2; ++ks)
                    acc[mt][nt] = __builtin_amdgcn_mfma_f32_16x16x32_bf16(bfr[nt][ks], af[mt][ks], acc[mt][nt], 0, 0, 0);
        __builtin_amdgcn_s_setprio(0);

        // ---- iter end: drain stages of t+1, flip --------------------------
        if (more) {
            asm volatile("s_waitcnt vmcnt(0)" ::: "memory");
            __builtin_amdgcn_s_barrier();
        }
    }

    // ---- epilogue: n = n0+wn2*64+nt*16+qd*4+rr, m = m0+wm2*64+mt*16+r16 ---
#pragma unroll
    for (int nt = 0; nt < 4; ++nt) {
        const int nb = n0 + wn2 * 64 + nt * 16 + qd * 4;
        const float4 bv = *(const float4*)&bias[nb];
        const float b4[4] = {bv.x, bv.y, bv.z, bv.w};
#pragma unroll
        for (int mi = 0; mi < 4; ++mi) {
            const int m = m0 + wm2 * 64 + mi * 16 + r16;
            __bf16 pk[4];
#pragma unroll
            for (int rr = 0; rr < 4; ++rr)
                pk[rr] = (__bf16)(acc[mi][nt][rr] + b4[rr]);
            *(bf16x4*)&Cout[(size_t)m * N + nb] = *(bf16x4*)pk;
        }
    }
}

// ---------------------------------------------------------------------------
// FF1: H1 = relu(X1 @ W1 + b1). 256x256 tile, BK=64, 512 thr = 8 waves
// (2M x 4N), 128KB dbuf LDS, XOR-swizzled, stages front-loaded (phases 1-2).
// Grid 32x8 = 256 blocks = 1/CU.
// ---------------------------------------------------------------------------
__global__ __launch_bounds__(512, 2)
void ff1_k(const u16* __restrict__ A, const u16* __restrict__ Bt,
           const float* __restrict__ bias, u16* __restrict__ C) {
    __shared__ __align__(16) u16 AB[2][32768];   // 128 KB
    const int tid = threadIdx.x, lane = tid & 63;
    const int w = tid >> 6;                       // 0..7
    const int wm2 = w >> 2, wn4 = w & 3;          // 2M x 4N
    const int r16 = lane & 15, qd = lane >> 4;
    const int qdx = (qd ^ ((r16 >> 1) & 3)) << 3; // swizzled read slot (u16)
    const int m0 = blockIdx.x * 256, n0 = blockIdx.y * 256;
    const int K = D_MODEL, NT = 12;

    const u16* aS[4]; const u16* bS[4];
#pragma unroll
    for (int l = 0; l < 4; ++l) {
        const int f = l * 512 + tid;
        const int row = (f >> 2) & 255, ks = f >> 10;
        const int e = (((f & 3) ^ ((f >> 3) & 3)) << 3);
        aS[l] = A  + (size_t)(m0 + row) * K + ks * 32 + e;
        bS[l] = Bt + (size_t)(n0 + row) * K + ks * 32 + e;
    }

    // prologue: stage tile 0
#pragma unroll
    for (int l = 0; l < 4; ++l) {
        gload_lds16(aS[l], &AB[0][(l * 512 + tid) * 8]);
        gload_lds16(bS[l], &AB[0][16384 + (l * 512 + tid) * 8]);
    }
    asm volatile("s_waitcnt vmcnt(0)" ::: "memory");
    __builtin_amdgcn_s_barrier();

    f32x4 acc[8][4] = {};
    bf16x8 af[4][2], bfr[4][2];
    const int arow0 = wm2 * 128 + r16;            // + mh*64 + mt*16
    const int brow0 = wn4 * 64 + r16;             // + nt*16

    for (int t = 0; t < NT; ++t) {
        const int cur = t & 1, nxt = cur ^ 1;
        const u16* ab = AB[cur];
        const int ka = (t + 1) * 64;              // k-offset of tile t+1
        const bool more = (t + 1) < NT;

        // ---- phase 1: af(mh=0) 8 + bfr(nt0,1) 4 reads; stage ALL 4 A' -----
#pragma unroll
        for (int mt = 0; mt < 4; ++mt)
#pragma unroll
            for (int ks = 0; ks < 2; ++ks)
                af[mt][ks] = *(const bf16x8*)&ab[ks * 8192 + (arow0 + mt * 16) * 32 + qdx];
#pragma unroll
        for (int nt = 0; nt < 2; ++nt)
#pragma unroll
            for (int ks = 0; ks < 2; ++ks)
                bfr[nt][ks] = *(const bf16x8*)&ab[16384 + ks * 8192 + (brow0 + nt * 16) * 32 + qdx];
        if (more) {
#pragma unroll
            for (int l = 0; l < 4; ++l)
                gload_lds16(aS[l] + ka, &AB[nxt][(l * 512 + tid) * 8]);
        }
        __builtin_amdgcn_s_setprio(1);
#pragma unroll
        for (int mt = 0; mt < 4; ++mt)
#pragma unroll
            for (int nt = 0; nt < 2; ++nt)
#pragma unroll
                for (int ks = 0; ks < 2; ++ks)
                    acc[mt][nt] = __builtin_amdgcn_mfma_f32_16x16x32_bf16(bfr[nt][ks], af[mt][ks], acc[mt][nt], 0, 0, 0);
        __builtin_amdgcn_s_setprio(0);
        __builtin_amdgcn_s_barrier();

        // ---- phase 2: bfr(nt2,3) 4 reads; stage ALL 4 B' ------------------
#pragma unroll
        for (int nt = 2; nt < 4; ++nt)
#pragma unroll
            for (int ks = 0; ks < 2; ++ks)
                bfr[nt][ks] = *(const bf16x8*)&ab[16384 + ks * 8192 + (brow0 + nt * 16) * 32 + qdx];
        if (more) {
#pragma unroll
            for (int l = 0; l < 4; ++l)
                gload_lds16(bS[l] + ka, &AB[nxt][16384 + (l * 512 + tid) * 8]);
        }
        __builtin_amdgcn_s_setprio(1);
#pragma unroll
        for (int mt = 0; mt < 4; ++mt)
#pragma unroll
            for (int nt = 2; nt < 4; ++nt)
#pragma unroll
                for (int ks = 0; ks < 2; ++ks)
                    acc[mt][nt] = __builtin_amdgcn_mfma_f32_16x16x32_bf16(bfr[nt][ks], af[mt][ks], acc[mt][nt], 0, 0, 0);
        __builtin_amdgcn_s_setprio(0);
        __builtin_amdgcn_s_barrier();

        // ---- phase 3: af(mh=1) 8 reads ------------------------------------
#pragma unroll
        for (int mt = 0; mt < 4; ++mt)
#pragma unroll
            for (int ks = 0; ks < 2; ++ks)
                af[mt][ks] = *(const bf16x8*)&ab[ks * 8192 + (arow0 + 64 + mt * 16) * 32 + qdx];
        __builtin_amdgcn_s_setprio(1);
#pragma unroll
        for (int mt = 0; mt < 4; ++mt)
#pragma unroll
            for (int nt = 0; nt < 2; ++nt)
#pragma unroll
                for (int ks = 0; ks < 2; ++ks)
                    acc[4 + mt][nt] = __builtin_amdgcn_mfma_f32_16x16x32_bf16(bfr[nt][ks], af[mt][ks], acc[4 + mt][nt], 0, 0, 0);
        __builtin_amdgcn_s_setprio(0);
        __builtin_amdgcn_s_barrier();

        // ---- phase 4 ------------------------------------------------------
        __builtin_amdgcn_s_setprio(1);
#pragma unroll
        for (int mt = 0; mt < 4; ++mt)
#pragma unroll
            for (int nt = 2; nt < 4; ++nt)
#pragma unroll
                for (int ks = 0; ks < 2; ++ks)
                    acc[4 + mt][nt] = __builtin_amdgcn_mfma_f32_16x16x32_bf16(bfr[nt][ks], af[mt][ks], acc[4 + mt][nt], 0, 0, 0);
        __builtin_amdgcn_s_setprio(0);

        // ---- iter end: drain stages of t+1 (issued 2-3 phases ago), flip --
        if (more) {
            asm volatile("s_waitcnt vmcnt(0)" ::: "memory");
            __builtin_amdgcn_s_barrier();
        }
    }

    // ---- epilogue: n = n0+wn4*64+nt*16+qd*4+rr, m = m0+wm2*128+mh*64+mt*16+r16
#pragma unroll
    for (int nt = 0; nt < 4; ++nt) {
        const int nb = n0 + wn4 * 64 + nt * 16 + qd * 4;
        const float4 bv = *(const float4*)&bias[nb];
        const float b4[4] = {bv.x, bv.y, bv.z, bv.w};
#pragma unroll
        for (int mi = 0; mi < 8; ++mi) {
            const int m = m0 + wm2 * 128 + (mi >> 2) * 64 + (mi & 3) * 16 + r16;
            __bf16 pk[4];
#pragma unroll
            for (int rr = 0; rr < 4; ++rr)
                pk[rr] = (__bf16)fmaxf(acc[mi][nt][rr] + b4[rr], 0.0f);
            *(bf16x4*)&C[(size_t)m * D_FF + nb] = *(bf16x4*)pk;
        }
    }
}

// ---------------------------------------------------------------------------
// Flash attention v9 "key-split" + T5 setprio. Block = 256 thr (4 waves),
// 128 q-rows, kt step 64, grid (16,12,4)=768 -> 3 independent blocks/CU.
// Wave w: qh = w&1 (q-rows qh*64..+63), kh = w>>1 (keys kh*32..+31 per tile).
// Max-free softmax => disjoint-key partials merge by ADDITION after kt loop.
// Layouts: Q,K [B,S,H,Dk]; Vt [B,H,Dk,S]; mask fp32 [B,S]; out [B,S,H*Dk].
// ---------------------------------------------------------------------------
#define TS 72   // LDS row stride (u16): 144 B, 16B-aligned, bank-spreading

__global__ __launch_bounds__(256, 3)
void attn_k(const u16* __restrict__ Qg, const u16* __restrict__ Kg,
            const u16* __restrict__ Vtg, const float* __restrict__ maskg,
            u16* __restrict__ Og) {
    const int tid = threadIdx.x, lane = tid & 63, w = tid >> 6;
    const int qh = w & 1, kh = w >> 1;
    const int r16 = lane & 15, qd = lane >> 4;
    const int q0 = blockIdx.x * 128;
    const int h = blockIdx.y, b = blockIdx.z;

    // one block so the O-merge buffer can overlay the whole tile space
    __shared__ __align__(16) u16 sm[(64 + 64 + 128) * TS];   // 36.9 KB
    u16* Ks  = sm;                  // [64 keys][64 feat]
    u16* Vts = sm + 64 * TS;        // [64 d][64 keys]
    u16* Ps  = sm + 128 * TS;       // [128 q][64 keys]

    // ---- Q fragments in registers (wave's 64 q-rows; same every kt) -------
    bf16x8 qa[4][2];
#pragma unroll
    for (int mt = 0; mt < 4; ++mt)
#pragma unroll
        for (int ks = 0; ks < 2; ++ks)
            qa[mt][ks] = *(const bf16x8*)(Qg +
                ((size_t)((b * S_LEN + q0 + qh * 64 + mt * 16 + r16) * NH + h)) * DK +
                ks * 32 + qd * 8);

    // ---- staging: 256 threads cover each 64x64 tile in 2 strips -----------
    const int srow = tid >> 3, sc = (tid & 7) << 3;
    const u16* vsrc = Vtg + (((size_t)(b * NH + h)) * DK) * S_LEN;   // [d][s]
    u16x8 kreg[2], vreg[2];
#pragma unroll
    for (int it = 0; it < 2; ++it) {
        const int row = srow + it * 32;
        kreg[it] = *(const u16x8*)(Kg + ((size_t)((b * S_LEN + row) * NH + h)) * DK + sc);
        vreg[it] = *(const u16x8*)(vsrc + (size_t)row * S_LEN + sc);
    }

    float l_i[4] = {0.0f, 0.0f, 0.0f, 0.0f};
    f32x4 Oacc[4][4] = {};

    for (int kt = 0; kt < S_LEN / 64; ++kt) {
        const int ks0 = kt * 64;

        // ---- commit prefetched K/Vt tiles to LDS --------------------------
#pragma unroll
        for (int it = 0; it < 2; ++it) {
            const int row = srow + it * 32;
            *(u16x8*)&Ks[row * TS + sc]  = kreg[it];
            *(u16x8*)&Vts[row * TS + sc] = vreg[it];
        }

        // ---- pre-scaled mask, this wave's 32 keys (key = kh*32+nt*16+qd*4+rr)
        float4 mrow[2];
#pragma unroll
        for (int nt = 0; nt < 2; ++nt) {
            const float4 mm = ((const float4*)(maskg + (size_t)b * S_LEN + ks0))[kh * 8 + nt * 4 + qd];
            mrow[nt].x = mm.x * MSCALE; mrow[nt].y = mm.y * MSCALE;
            mrow[nt].z = mm.z * MSCALE; mrow[nt].w = mm.w * MSCALE;
        }
        __syncthreads();

        // ---- S^T = K @ Q^T + mask (mask as acc init); keys kh*32..+31 -----
        f32x4 sa[4][2];
#pragma unroll
        for (int mt = 0; mt < 4; ++mt)
#pragma unroll
            for (int nt = 0; nt < 2; ++nt) {
                sa[mt][nt][0] = mrow[nt].x; sa[mt][nt][1] = mrow[nt].y;
                sa[mt][nt][2] = mrow[nt].z; sa[mt][nt][3] = mrow[nt].w;
            }
#pragma unroll
        for (int ks = 0; ks < 2; ++ks) {
            bf16x8 kb[2];
#pragma unroll
            for (int nt = 0; nt < 2; ++nt)
                kb[nt] = *(const bf16x8*)&Ks[(kh * 32 + nt * 16 + r16) * TS + ks * 32 + qd * 8];
            __builtin_amdgcn_s_setprio(1);
#pragma unroll
            for (int mt = 0; mt < 4; ++mt)
#pragma unroll
                for (int nt = 0; nt < 2; ++nt)
                    sa[mt][nt] = __builtin_amdgcn_mfma_f32_16x16x32_bf16(kb[nt], qa[mt][ks], sa[mt][nt], 0, 0, 0);
            __builtin_amdgcn_s_setprio(0);
        }

        // ---- max-free softmax partial: p = exp2(s), l += sum (32 keys) ----
#pragma unroll
        for (int mt = 0; mt < 4; ++mt) {
            float rsum = 0.0f;
#pragma unroll
            for (int nt = 0; nt < 2; ++nt) {
                sa[mt][nt][0] = __builtin_amdgcn_exp2f(sa[mt][nt][0]);
                sa[mt][nt][1] = __builtin_amdgcn_exp2f(sa[mt][nt][1]);
                sa[mt][nt][2] = __builtin_amdgcn_exp2f(sa[mt][nt][2]);
                sa[mt][nt][3] = __builtin_amdgcn_exp2f(sa[mt][nt][3]);
                rsum += sa[mt][nt][0] + sa[mt][nt][1] + sa[mt][nt][2] + sa[mt][nt][3];
            }
            rsum += __shfl_xor(rsum, 16);
            rsum += __shfl_xor(rsum, 32);
            l_i[mt] += rsum;   // uniform across qd for fixed r16 (q = mt*16+r16)
        }

        // ---- P -> Ps [q][key], wave-private 64x32 block -------------------
#pragma unroll
        for (int mt = 0; mt < 4; ++mt)
#pragma unroll
            for (int nt = 0; nt < 2; ++nt) {
                __bf16 pk[4];
#pragma unroll
                for (int rr = 0; rr < 4; ++rr) pk[rr] = (__bf16)sa[mt][nt][rr];
                *(bf16x4*)&Ps[(qh * 64 + mt * 16 + r16) * TS + kh * 32 + nt * 16 + qd * 4] = *(bf16x4*)pk;
            }

        // ---- issue next tile's global loads (sa dead; caps VGPR peak) -----
        if (kt + 1 < S_LEN / 64) {
            const int ns0 = ks0 + 64;
#pragma unroll
            for (int it = 0; it < 2; ++it) {
                const int row = srow + it * 32;
                kreg[it] = *(const u16x8*)(Kg + ((size_t)((b * S_LEN + ns0 + row) * NH + h)) * DK + sc);
                vreg[it] = *(const u16x8*)(vsrc + (size_t)row * S_LEN + ns0 + sc);
            }
        }

        // ---- O += P @ V over this wave's 32 keys --------------------------
        {
            bf16x8 pa[4], vb[4];
#pragma unroll
            for (int mt = 0; mt < 4; ++mt)
                pa[mt] = *(const bf16x8*)&Ps[(qh * 64 + mt * 16 + r16) * TS + kh * 32 + qd * 8];
#pragma unroll
            for (int vt = 0; vt < 4; ++vt)
                vb[vt] = *(const bf16x8*)&Vts[(vt * 16 + r16) * TS + kh * 32 + qd * 8];
            __builtin_amdgcn_s_setprio(1);
#pragma unroll
            for (int mt = 0; mt < 4; ++mt)
#pragma unroll
                for (int vt = 0; vt < 4; ++vt)
                    Oacc[mt][vt] = __builtin_amdgcn_mfma_f32_16x16x32_bf16(pa[mt], vb[vt], Oacc[mt][vt], 0, 0, 0);
            __builtin_amdgcn_s_setprio(0);
        }
        __syncthreads();   // all waves done with Ks/Vts/Ps before next commit
    }

    // ---- merge kh partials (addition; max-free softmax) -------------------
    __syncthreads();                       // tile space dead, safe to overlay
    float* mb  = (float*)sm;               // [128 q][64 d] fp32 = 32 KB
    float* lsm = mb + 128 * 64;            // [2 qh][4 mt][16 r16] = 512 B
    if (kh == 0) {
#pragma unroll
        for (int mt = 0; mt < 4; ++mt) {
            if (qd == 0) lsm[(qh * 4 + mt) * 16 + r16] = l_i[mt];
#pragma unroll
            for (int vt = 0; vt < 4; ++vt)
#pragma unroll
                for (int rr = 0; rr < 4; ++rr)
                    mb[(qh * 64 + mt * 16 + qd * 4 + rr) * 64 + vt * 16 + r16] = Oacc[mt][vt][rr];
        }
    }
    __syncthreads();
    if (kh == 1) {
#pragma unroll
        for (int mt = 0; mt < 4; ++mt) {
            const float linv = 1.0f / (l_i[mt] + lsm[(qh * 4 + mt) * 16 + r16]);
#pragma unroll
            for (int rr = 0; rr < 4; ++rr) {
                const float lr = __shfl(linv, qd * 4 + rr);
                const int qrow = q0 + qh * 64 + mt * 16 + qd * 4 + rr;
#pragma unroll
                for (int vt = 0; vt < 4; ++vt) {
                    const float o = Oacc[mt][vt][rr] +
                        mb[(qh * 64 + mt * 16 + qd * 4 + rr) * 64 + vt * 16 + r16];
                    st_bf(&Og[((size_t)((b * S_LEN + qrow) * NH + h)) * DK + vt * 16 + r16],
                          o * lr);
                }
            }
        }
    }
}

// ---------------------------------------------------------------------------
// Residual + LayerNorm over D=768. Inputs bf16 x + bf16 y; fp32 math.
// ---------------------------------------------------------------------------
__global__ __launch_bounds__(256, 4)
void resln_k(const u16* __restrict__ xb, const u16* __restrict__ yb,
             const float* __restrict__ gamma, const float* __restrict__ beta,
             u16* __restrict__ outb, float* __restrict__ outf) {
    const int row = blockIdx.x, tid = threadIdx.x;
    const int lane = tid & 63, w = tid >> 6;
    __shared__ float redS[4], redS2[4];
    const size_t base = (size_t)row * D_MODEL;
    float h[3], s = 0.0f, s2 = 0.0f;
#pragma unroll
    for (int i = 0; i < 3; ++i) {
        const int c = i * 256 + tid;
        const float v = bf2f(xb[base + c]) + bf2f(yb[base + c]);
        h[i] = v; s += v; s2 += v * v;
    }
#pragma unroll
    for (int off = 32; off >= 1; off >>= 1) { s += __shfl_xor(s, off); s2 += __shfl_xor(s2, off); }
    if (lane == 0) { redS[w] = s; redS2[w] = s2; }
    __syncthreads();
    s  = redS[0] + redS[1] + redS[2] + redS[3];
    s2 = redS2[0] + redS2[1] + redS2[2] + redS2[3];
    const float mu  = s * (1.0f / D_MODEL);
    const float var = s2 * (1.0f / D_MODEL) - mu * mu;
    const float rstd = rsqrtf(var + 1e-3f);
#pragma unroll
    for (int i = 0; i < 3; ++i) {
        const int c = i * 256 + tid;
        const float o = (h[i] - mu) * rstd * gamma[c] + beta[c];
        if (outb) st_bf(&outb[base + c], o);
        if (outf) outf[base + c] = o;
    }
}

// ---------------------------------------------------------------------------
extern "C" void kernel_launch(void* const* d_in, const int* in_sizes, int n_in,
                              void* d_out, int out_size, void* d_ws, size_t ws_size,
                              hipStream_t stream) {
    (void)in_sizes; (void)n_in; (void)out_size; (void)ws_size;
    const float* x    = (const float*)d_in[0];
    const float* mask = (const float*)d_in[1];
    const float* Wq = (const float*)d_in[2];  const float* bq  = (const float*)d_in[3];
    const float* Wk = (const float*)d_in[4];  const float* bk  = (const float*)d_in[5];
    const float* Wv = (const float*)d_in[6];  const float* bv  = (const float*)d_in[7];
    const float* Wo = (const float*)d_in[8];  const float* bo  = (const float*)d_in[9];
    const float* W1 = (const float*)d_in[10]; const float* b1  = (const float*)d_in[11];
    const float* W2 = (const float*)d_in[12]; const float* b2  = (const float*)d_in[13];
    const float* g1 = (const float*)d_in[14]; const float* be1 = (const float*)d_in[15];
    const float* g2 = (const float*)d_in[16]; const float* be2 = (const float*)d_in[17];

    char* ws = (char*)d_ws;
    u16* xb     = (u16*)(ws + 0);            // 12,582,912
    u16* WqkvT  = (u16*)(ws + 12582912);     //  3,538,944
    u16* WoT    = (u16*)(ws + 16121856);     //  1,179,648
    u16* W1T    = (u16*)(ws + 17301504);     //  3,145,728
    u16* W2T    = (u16*)(ws + 20447232);     //  3,145,728
    u16* Qb     = (u16*)(ws + 23592960);     // 12,582,912
    u16* Kb     = (u16*)(ws + 36175872);     // 12,582,912
    u16* Vtg    = (u16*)(ws + 48758784);     // 12,582,912 [B,H,Dk,S]
    u16* Ab     = (u16*)(ws + 61341696);     // 12,582,912
    u16* Yb     = (u16*)(ws + 73924608);     // 12,582,912
    u16* X1b    = (u16*)(ws + 86507520);     // 12,582,912 (end ~99 MB)
    u16* H1b    = (u16*)(ws + 23592960);     // reuse Qb/Kb/Vtg (dead after attn)
    u16* Y2b    = (u16*)(ws + 73924608);     // reuse Yb (dead after LN1)

    const dim3 blk(256);

    // 0. fused prep: x->bf16 + all 6 weight transposes (one dispatch)
    prep_k<<<dim3(11520), blk, 0, stream>>>(x, Wq, Wk, Wv, Wo, W1, W2,
                                            xb, WqkvT, WoT, W1T, W2T);

    // 1. fused QKV projection: 128^2 4-phase, proven epilogue (1152 blocks)
    qkv4p_k<<<dim3(64, 18), blk, 0, stream>>>(xb, WqkvT, bq, bk, bv, Qb, Kb, Vtg);

    // 2. flash attention v9 (key-split waves + setprio)
    attn_k<<<dim3(16, NH, 4), blk, 0, stream>>>(Qb, Kb, Vtg, mask, Ab);

    // 3. output projection: 128^2 4-phase (384 blocks, 2/CU resident)
    g4p_k<<<dim3(64, 6), blk, 0, stream>>>(Ab, WoT, bo, Yb, D_MODEL, D_MODEL);

    // 4. LN1: x1 = LN(x + Y) -> bf16
    resln_k<<<dim3(M_TOK), blk, 0, stream>>>(xb, Yb, g1, be1, X1b, nullptr);

    // 5. FF1: H1 = relu(x1@W1 + b1), 256^2 4-phase (front-loaded stages)
    ff1_k<<<dim3(32, 8), dim3(512), 0, stream>>>(X1b, W1T, b1, H1b);

    // 6. FF2: 128^2 4-phase (384 blocks, NT=32)
    g4p_k<<<dim3(64, 6), blk, 0, stream>>>(H1b, W2T, b2, Y2b, D_MODEL, D_FF);

    // 7. LN2: out = LN(x1 + Y2) fp32 -> d_out
    resln_k<<<dim3(M_TOK), blk, 0, stream>>>(X1b, Y2b, g2, be2, nullptr, (float*)d_out);
}

// Round 13
// 328.002 us; speedup vs baseline: 1.0558x; 1.0157x over previous
//
#include <hip/hip_runtime.h>

// ---------------------------------------------------------------------------
// EncoderLayer on MI355X (gfx950). fp32 in/out, bf16 MFMA compute inside.
// B=4 S=2048 D=768 H=12 Dk=64 Dff=2048, M = B*S = 8192 tokens.
//
// Round 19: QKV reverted to r16's 2-phase (256,3) kernel (4-phase variant
// measured worse: 2/CU + 2.25 rounds + scalar QK stores lose to 3/CU TLP).
// resln_k rewritten: one wave per row (4 rows/block, grid 2048), u16x4
// vectorized loads, wave-local shfl reduce (no LDS/barrier), bf16x4/float4
// stores. Everything else = r16 (g4p Wo+FF2, ff1 256^2, attn v9+T5).
// ---------------------------------------------------------------------------

typedef unsigned short u16;
typedef __bf16 bf16x8 __attribute__((ext_vector_type(8)));
typedef __bf16 bf16x4 __attribute__((ext_vector_type(4)));
typedef unsigned short u16x8 __attribute__((ext_vector_type(8)));
typedef unsigned short u16x4 __attribute__((ext_vector_type(4)));
typedef float f32x4 __attribute__((ext_vector_type(4)));

#define D_MODEL 768
#define D_FF    2048
#define NH      12
#define DK      64
#define S_LEN   2048
#define M_TOK   8192

#define QSCALE   0.18033688011112042f   /* 0.125 * log2(e) */
#define MSCALE  -1.4426950408889634e9f  /* -1e9 * log2(e)  */

__device__ __forceinline__ float bf2f(u16 v) {
    union { unsigned u; float f; } c; c.u = ((unsigned)v) << 16; return c.f;
}
__device__ __forceinline__ void st_bf(u16* p, float v) { *(__bf16*)p = (__bf16)v; }

// async global->LDS, 16B/lane; LDS dest must be wave-uniform base + lane*16.
__device__ __forceinline__ void gload_lds16(const void* g, void* l) {
    __builtin_amdgcn_global_load_lds(
        (const __attribute__((address_space(1))) void*)g,
        (__attribute__((address_space(3))) void*)l, 16, 0, 0);
}

// ---------------------------------------------------------------------------
// Fused prep: blocks [0,2304) = 4x 768x768 transposes; [2304,3840) = W1
// (768x2048); [3840,5376) = W2 (2048x768); [5376,11520) = x fp32->bf16.
// ---------------------------------------------------------------------------
__global__ __launch_bounds__(256)
void prep_k(const float* __restrict__ x, const float* __restrict__ Wq,
            const float* __restrict__ Wk, const float* __restrict__ Wv,
            const float* __restrict__ Wo, const float* __restrict__ W1,
            const float* __restrict__ W2, u16* __restrict__ xb,
            u16* __restrict__ WqkvT, u16* __restrict__ WoT,
            u16* __restrict__ W1T, u16* __restrict__ W2T) {
    __shared__ float t[32][33];
    const int id = blockIdx.x, tid = threadIdx.x;
    if (id >= 5376) {               // ---- x convert ----
        const int i = ((id - 5376) * 256 + tid) * 4;
        const float4 v = *(const float4*)(x + i);
        __bf16 o[4] = {(__bf16)v.x, (__bf16)v.y, (__bf16)v.z, (__bf16)v.w};
        *(bf16x4*)(xb + i) = *(bf16x4*)o;
        return;
    }
    const float* in; u16* out; int R, C, bx, by;
    if (id < 2304) {                // ---- Wq/Wk/Wv/Wo 768x768 ----
        const int z = id / 576, r = id % 576;
        in = z == 0 ? Wq : (z == 1 ? Wk : (z == 2 ? Wv : Wo));
        out = z == 3 ? WoT : WqkvT + z * 768 * 768;
        R = 768; C = 768; bx = (r % 24) * 32; by = (r / 24) * 32;
    } else if (id < 3840) {         // ---- W1 [768,2048] -> [2048,768] ----
        const int r = id - 2304;
        in = W1; out = W1T; R = 768; C = 2048;
        bx = (r % 64) * 32; by = (r / 64) * 32;
    } else {                        // ---- W2 [2048,768] -> [768,2048] ----
        const int r = id - 3840;
        in = W2; out = W2T; R = 2048; C = 768;
        bx = (r % 24) * 32; by = (r / 24) * 32;
    }
    const int tx = tid & 31, ty = tid >> 5;
#pragma unroll
    for (int i = 0; i < 32; i += 8)
        t[ty + i][tx] = in[(size_t)(by + ty + i) * C + bx + tx];
    __syncthreads();
#pragma unroll
    for (int i = 0; i < 32; i += 8)
        st_bf(&out[(size_t)(bx + ty + i) * R + by + tx], t[tx][ty + i]);
}

// ---------------------------------------------------------------------------
// Fused QKV GEMM, 128x128 tile, BK=64 (two BK=32 panels), swizzled LDS,
// 2-phase, (256,3) -> 3 blocks/CU. n in [0,768): Q*QSCALE -> Qb;
// [768,1536): K -> Kb; [1536,2304): V -> Vt (pre-transposed [B,H,Dk,S]).
// ---------------------------------------------------------------------------
__global__ __launch_bounds__(256, 3)
void qkv_gemm_k(const u16* __restrict__ A, const u16* __restrict__ Bt,
                const float* __restrict__ bq, const float* __restrict__ bk,
                const float* __restrict__ bv, u16* __restrict__ Qb,
                u16* __restrict__ Kb, u16* __restrict__ Vt) {
    __shared__ __align__(16) u16 As[2][128 * 32];
    __shared__ __align__(16) u16 Bs[2][128 * 32];
    const int tid = threadIdx.x;
    const int lane = tid & 63, w = tid >> 6;
    const int r16 = lane & 15, qd = lane >> 4;
    const int qdx = (qd ^ ((r16 >> 1) & 3)) << 3;   // swizzled read slot (u16)
    const int m0 = blockIdx.x * 128, n0 = blockIdx.y * 128;
    const int wm = (w & 1) << 6, wn = (w >> 1) << 6;
    const int K = D_MODEL;

    f32x4 acc[4][4] = {};

    const u16* aP[2]; const u16* bP[2]; int f8[2];
#pragma unroll
    for (int it = 0; it < 2; ++it) {
        const int f = it * 256 + tid;
        const int row = f >> 2;
        const int kc = ((f & 3) ^ ((f >> 3) & 3)) << 3;  // pre-swizzled source
        aP[it] = A  + (size_t)(m0 + row) * K + kc;
        bP[it] = Bt + (size_t)(n0 + row) * K + kc;
        f8[it] = f * 8;
    }

    for (int k0 = 0; k0 < K; k0 += 64) {
#pragma unroll
        for (int p = 0; p < 2; ++p)
#pragma unroll
            for (int it = 0; it < 2; ++it) {
                gload_lds16(aP[it] + k0 + p * 32, &As[p][f8[it]]);
                gload_lds16(bP[it] + k0 + p * 32, &Bs[p][f8[it]]);
            }
        __syncthreads();
#pragma unroll
        for (int p = 0; p < 2; ++p) {
            bf16x8 af[4], bfr[4];
#pragma unroll
            for (int i = 0; i < 4; ++i) {
                af[i]  = *(const bf16x8*)&As[p][(wm + i * 16 + r16) * 32 + qdx];
                bfr[i] = *(const bf16x8*)&Bs[p][(wn + i * 16 + r16) * 32 + qdx];
            }
#pragma unroll
            for (int i = 0; i < 4; ++i)
#pragma unroll
                for (int j = 0; j < 4; ++j)
                    acc[i][j] = __builtin_amdgcn_mfma_f32_16x16x32_bf16(af[i], bfr[j], acc[i][j], 0, 0, 0);
        }
        __syncthreads();
    }

    const int sel = n0 < 768 ? 0 : (n0 < 1536 ? 1 : 2);
    const float* bias = sel == 0 ? bq : (sel == 1 ? bk : bv);
    const float scale = sel == 0 ? QSCALE : 1.0f;
    const int nbase = n0 - sel * 768;

#pragma unroll
    for (int j = 0; j < 4; ++j) {
        const int ncol = nbase + wn + j * 16 + r16;
        const float bvv = bias[ncol];
#pragma unroll
        for (int i = 0; i < 4; ++i) {
            if (sel == 2) {
                // V: pack 4 consecutive s-positions into one b64 store
                const int h = ncol >> 6, d = ncol & 63;
                const int mb = m0 + wm + i * 16 + qd * 4;
                const int bb = mb >> 11, npb = mb & 2047;
                __bf16 pk[4];
#pragma unroll
                for (int rr = 0; rr < 4; ++rr) pk[rr] = (__bf16)(acc[i][j][rr] + bvv);
                *(bf16x4*)&Vt[(((size_t)(bb * NH + h)) * DK + d) * S_LEN + npb] = *(bf16x4*)pk;
            } else {
#pragma unroll
                for (int rr = 0; rr < 4; ++rr) {
                    const int m = m0 + wm + i * 16 + qd * 4 + rr;
                    const float v = (acc[i][j][rr] + bvv) * scale;
                    if (sel == 0) st_bf(&Qb[(size_t)m * D_MODEL + ncol], v);
                    else          st_bf(&Kb[(size_t)m * D_MODEL + ncol], v);
                }
            }
        }
    }
}

// ---------------------------------------------------------------------------
// g4p: 128x128 4-phase GEMM (Wo + FF2). C = A @ Bt^T + bias. 256 thr =
// 4 waves (2M x 2N), per-wave output 64x64. LDS 64KB dbuf, swizzled.
// ---------------------------------------------------------------------------
__global__ __launch_bounds__(256, 2)
void g4p_k(const u16* __restrict__ A, const u16* __restrict__ Bt,
           const float* __restrict__ bias, u16* __restrict__ Cout,
           int N, int K) {
    __shared__ __align__(16) u16 AB[2][16384];   // 64 KB
    const int tid = threadIdx.x, lane = tid & 63;
    const int w = tid >> 6;                       // 0..3
    const int wm2 = w >> 1, wn2 = w & 1;          // 2M x 2N
    const int r16 = lane & 15, qd = lane >> 4;
    const int qdx = (qd ^ ((r16 >> 1) & 3)) << 3; // swizzled read slot (u16)
    const int m0 = blockIdx.x * 128, n0 = blockIdx.y * 128;
    const int NT = K >> 6;

    const u16* aS[4]; const u16* bS[4];
#pragma unroll
    for (int l = 0; l < 4; ++l) {
        const int f = l * 256 + tid;
        const int row = (f >> 2) & 127, ks = f >> 9;
        const int e = (((f & 3) ^ ((f >> 3) & 3)) << 3);
        aS[l] = A  + (size_t)(m0 + row) * K + ks * 32 + e;
        bS[l] = Bt + (size_t)(n0 + row) * K + ks * 32 + e;
    }

    // prologue: stage tile 0
#pragma unroll
    for (int l = 0; l < 4; ++l) {
        gload_lds16(aS[l], &AB[0][(l * 256 + tid) * 8]);
        gload_lds16(bS[l], &AB[0][8192 + (l * 256 + tid) * 8]);
    }
    asm volatile("s_waitcnt vmcnt(0)" ::: "memory");
    __builtin_amdgcn_s_barrier();

    f32x4 acc[4][4] = {};
    bf16x8 af[4][2], bfr[4][2];
    const int arow0 = wm2 * 64 + r16;             // + mt*16
    const int brow0 = wn2 * 64 + r16;             // + nt*16

    for (int t = 0; t < NT; ++t) {
        const int cur = t & 1, nxt = cur ^ 1;
        const u16* ab = AB[cur];
        const int ka = (t + 1) * 64;
        const bool more = (t + 1) < NT;

        // ---- phase 1: af 8 + bfr(nt0,1) 4 reads; stage ALL 4 A' -----------
#pragma unroll
        for (int mt = 0; mt < 4; ++mt)
#pragma unroll
            for (int ks = 0; ks < 2; ++ks)
                af[mt][ks] = *(const bf16x8*)&ab[ks * 4096 + (arow0 + mt * 16) * 32 + qdx];
#pragma unroll
        for (int nt = 0; nt < 2; ++nt)
#pragma unroll
            for (int ks = 0; ks < 2; ++ks)
                bfr[nt][ks] = *(const bf16x8*)&ab[8192 + ks * 4096 + (brow0 + nt * 16) * 32 + qdx];
        if (more) {
#pragma unroll
            for (int l = 0; l < 4; ++l)
                gload_lds16(aS[l] + ka, &AB[nxt][(l * 256 + tid) * 8]);
        }
        __builtin_amdgcn_s_setprio(1);
#pragma unroll
        for (int mt = 0; mt < 4; ++mt)
#pragma unroll
            for (int nt = 0; nt < 2; ++nt)
#pragma unroll
                for (int ks = 0; ks < 2; ++ks)
                    acc[mt][nt] = __builtin_amdgcn_mfma_f32_16x16x32_bf16(bfr[nt][ks], af[mt][ks], acc[mt][nt], 0, 0, 0);
        __builtin_amdgcn_s_setprio(0);
        __builtin_amdgcn_s_barrier();

        // ---- phase 2: bfr(nt2,3) 4 reads; stage ALL 4 B' ------------------
#pragma unroll
        for (int nt = 2; nt < 4; ++nt)
#pragma unroll
            for (int ks = 0; ks < 2; ++ks)
                bfr[nt][ks] = *(const bf16x8*)&ab[8192 + ks * 4096 + (brow0 + nt * 16) * 32 + qdx];
        if (more) {
#pragma unroll
            for (int l = 0; l < 4; ++l)
                gload_lds16(bS[l] + ka, &AB[nxt][8192 + (l * 256 + tid) * 8]);
        }
        __builtin_amdgcn_s_setprio(1);
#pragma unroll
        for (int mt = 0; mt < 4; ++mt)
#pragma unroll
            for (int nt = 2; nt < 4; ++nt)
#pragma unroll
                for (int ks = 0; ks < 2; ++ks)
                    acc[mt][nt] = __builtin_amdgcn_mfma_f32_16x16x32_bf16(bfr[nt][ks], af[mt][ks], acc[mt][nt], 0, 0, 0);
        __builtin_amdgcn_s_setprio(0);

        // ---- iter end: drain stages of t+1, flip --------------------------
        if (more) {
            asm volatile("s_waitcnt vmcnt(0)" ::: "memory");
            __builtin_amdgcn_s_barrier();
        }
    }

    // ---- epilogue: n = n0+wn2*64+nt*16+qd*4+rr, m = m0+wm2*64+mt*16+r16 ---
#pragma unroll
    for (int nt = 0; nt < 4; ++nt) {
        const int nb = n0 + wn2 * 64 + nt * 16 + qd * 4;
        const float4 bv = *(const float4*)&bias[nb];
        const float b4[4] = {bv.x, bv.y, bv.z, bv.w};
#pragma unroll
        for (int mi = 0; mi < 4; ++mi) {
            const int m = m0 + wm2 * 64 + mi * 16 + r16;
            __bf16 pk[4];
#pragma unroll
            for (int rr = 0; rr < 4; ++rr)
                pk[rr] = (__bf16)(acc[mi][nt][rr] + b4[rr]);
            *(bf16x4*)&Cout[(size_t)m * N + nb] = *(bf16x4*)pk;
        }
    }
}

// ---------------------------------------------------------------------------
// FF1: H1 = relu(X1 @ W1 + b1). 256x256 tile, BK=64, 512 thr = 8 waves
// (2M x 4N), 128KB dbuf LDS, XOR-swizzled, stages front-loaded (phases 1-2).
// Grid 32x8 = 256 blocks = 1/CU.
// ---------------------------------------------------------------------------
__global__ __launch_bounds__(512, 2)
void ff1_k(const u16* __restrict__ A, const u16* __restrict__ Bt,
           const float* __restrict__ bias, u16* __restrict__ C) {
    __shared__ __align__(16) u16 AB[2][32768];   // 128 KB
    const int tid = threadIdx.x, lane = tid & 63;
    const int w = tid >> 6;                       // 0..7
    const int wm2 = w >> 2, wn4 = w & 3;          // 2M x 4N
    const int r16 = lane & 15, qd = lane >> 4;
    const int qdx = (qd ^ ((r16 >> 1) & 3)) << 3; // swizzled read slot (u16)
    const int m0 = blockIdx.x * 256, n0 = blockIdx.y * 256;
    const int K = D_MODEL, NT = 12;

    const u16* aS[4]; const u16* bS[4];
#pragma unroll
    for (int l = 0; l < 4; ++l) {
        const int f = l * 512 + tid;
        const int row = (f >> 2) & 255, ks = f >> 10;
        const int e = (((f & 3) ^ ((f >> 3) & 3)) << 3);
        aS[l] = A  + (size_t)(m0 + row) * K + ks * 32 + e;
        bS[l] = Bt + (size_t)(n0 + row) * K + ks * 32 + e;
    }

    // prologue: stage tile 0
#pragma unroll
    for (int l = 0; l < 4; ++l) {
        gload_lds16(aS[l], &AB[0][(l * 512 + tid) * 8]);
        gload_lds16(bS[l], &AB[0][16384 + (l * 512 + tid) * 8]);
    }
    asm volatile("s_waitcnt vmcnt(0)" ::: "memory");
    __builtin_amdgcn_s_barrier();

    f32x4 acc[8][4] = {};
    bf16x8 af[4][2], bfr[4][2];
    const int arow0 = wm2 * 128 + r16;            // + mh*64 + mt*16
    const int brow0 = wn4 * 64 + r16;             // + nt*16

    for (int t = 0; t < NT; ++t) {
        const int cur = t & 1, nxt = cur ^ 1;
        const u16* ab = AB[cur];
        const int ka = (t + 1) * 64;              // k-offset of tile t+1
        const bool more = (t + 1) < NT;

        // ---- phase 1: af(mh=0) 8 + bfr(nt0,1) 4 reads; stage ALL 4 A' -----
#pragma unroll
        for (int mt = 0; mt < 4; ++mt)
#pragma unroll
            for (int ks = 0; ks < 2; ++ks)
                af[mt][ks] = *(const bf16x8*)&ab[ks * 8192 + (arow0 + mt * 16) * 32 + qdx];
#pragma unroll
        for (int nt = 0; nt < 2; ++nt)
#pragma unroll
            for (int ks = 0; ks < 2; ++ks)
                bfr[nt][ks] = *(const bf16x8*)&ab[16384 + ks * 8192 + (brow0 + nt * 16) * 32 + qdx];
        if (more) {
#pragma unroll
            for (int l = 0; l < 4; ++l)
                gload_lds16(aS[l] + ka, &AB[nxt][(l * 512 + tid) * 8]);
        }
        __builtin_amdgcn_s_setprio(1);
#pragma unroll
        for (int mt = 0; mt < 4; ++mt)
#pragma unroll
            for (int nt = 0; nt < 2; ++nt)
#pragma unroll
                for (int ks = 0; ks < 2; ++ks)
                    acc[mt][nt] = __builtin_amdgcn_mfma_f32_16x16x32_bf16(bfr[nt][ks], af[mt][ks], acc[mt][nt], 0, 0, 0);
        __builtin_amdgcn_s_setprio(0);
        __builtin_amdgcn_s_barrier();

        // ---- phase 2: bfr(nt2,3) 4 reads; stage ALL 4 B' ------------------
#pragma unroll
        for (int nt = 2; nt < 4; ++nt)
#pragma unroll
            for (int ks = 0; ks < 2; ++ks)
                bfr[nt][ks] = *(const bf16x8*)&ab[16384 + ks * 8192 + (brow0 + nt * 16) * 32 + qdx];
        if (more) {
#pragma unroll
            for (int l = 0; l < 4; ++l)
                gload_lds16(bS[l] + ka, &AB[nxt][16384 + (l * 512 + tid) * 8]);
        }
        __builtin_amdgcn_s_setprio(1);
#pragma unroll
        for (int mt = 0; mt < 4; ++mt)
#pragma unroll
            for (int nt = 2; nt < 4; ++nt)
#pragma unroll
                for (int ks = 0; ks < 2; ++ks)
                    acc[mt][nt] = __builtin_amdgcn_mfma_f32_16x16x32_bf16(bfr[nt][ks], af[mt][ks], acc[mt][nt], 0, 0, 0);
        __builtin_amdgcn_s_setprio(0);
        __builtin_amdgcn_s_barrier();

        // ---- phase 3: af(mh=1) 8 reads ------------------------------------
#pragma unroll
        for (int mt = 0; mt < 4; ++mt)
#pragma unroll
            for (int ks = 0; ks < 2; ++ks)
                af[mt][ks] = *(const bf16x8*)&ab[ks * 8192 + (arow0 + 64 + mt * 16) * 32 + qdx];
        __builtin_amdgcn_s_setprio(1);
#pragma unroll
        for (int mt = 0; mt < 4; ++mt)
#pragma unroll
            for (int nt = 0; nt < 2; ++nt)
#pragma unroll
                for (int ks = 0; ks < 2; ++ks)
                    acc[4 + mt][nt] = __builtin_amdgcn_mfma_f32_16x16x32_bf16(bfr[nt][ks], af[mt][ks], acc[4 + mt][nt], 0, 0, 0);
        __builtin_amdgcn_s_setprio(0);
        __builtin_amdgcn_s_barrier();

        // ---- phase 4 ------------------------------------------------------
        __builtin_amdgcn_s_setprio(1);
#pragma unroll
        for (int mt = 0; mt < 4; ++mt)
#pragma unroll
            for (int nt = 2; nt < 4; ++nt)
#pragma unroll
                for (int ks = 0; ks < 2; ++ks)
                    acc[4 + mt][nt] = __builtin_amdgcn_mfma_f32_16x16x32_bf16(bfr[nt][ks], af[mt][ks], acc[4 + mt][nt], 0, 0, 0);
        __builtin_amdgcn_s_setprio(0);

        // ---- iter end: drain stages of t+1 (issued 2-3 phases ago), flip --
        if (more) {
            asm volatile("s_waitcnt vmcnt(0)" ::: "memory");
            __builtin_amdgcn_s_barrier();
        }
    }

    // ---- epilogue: n = n0+wn4*64+nt*16+qd*4+rr, m = m0+wm2*128+mh*64+mt*16+r16
#pragma unroll
    for (int nt = 0; nt < 4; ++nt) {
        const int nb = n0 + wn4 * 64 + nt * 16 + qd * 4;
        const float4 bv = *(const float4*)&bias[nb];
        const float b4[4] = {bv.x, bv.y, bv.z, bv.w};
#pragma unroll
        for (int mi = 0; mi < 8; ++mi) {
            const int m = m0 + wm2 * 128 + (mi >> 2) * 64 + (mi & 3) * 16 + r16;
            __bf16 pk[4];
#pragma unroll
            for (int rr = 0; rr < 4; ++rr)
                pk[rr] = (__bf16)fmaxf(acc[mi][nt][rr] + b4[rr], 0.0f);
            *(bf16x4*)&C[(size_t)m * D_FF + nb] = *(bf16x4*)pk;
        }
    }
}

// ---------------------------------------------------------------------------
// Flash attention v9 "key-split" + T5 setprio. Block = 256 thr (4 waves),
// 128 q-rows, kt step 64, grid (16,12,4)=768 -> 3 independent blocks/CU.
// Wave w: qh = w&1 (q-rows qh*64..+63), kh = w>>1 (keys kh*32..+31 per tile).
// Max-free softmax => disjoint-key partials merge by ADDITION after kt loop.
// Layouts: Q,K [B,S,H,Dk]; Vt [B,H,Dk,S]; mask fp32 [B,S]; out [B,S,H*Dk].
// ---------------------------------------------------------------------------
#define TS 72   // LDS row stride (u16): 144 B, 16B-aligned, bank-spreading

__global__ __launch_bounds__(256, 3)
void attn_k(const u16* __restrict__ Qg, const u16* __restrict__ Kg,
            const u16* __restrict__ Vtg, const float* __restrict__ maskg,
            u16* __restrict__ Og) {
    const int tid = threadIdx.x, lane = tid & 63, w = tid >> 6;
    const int qh = w & 1, kh = w >> 1;
    const int r16 = lane & 15, qd = lane >> 4;
    const int q0 = blockIdx.x * 128;
    const int h = blockIdx.y, b = blockIdx.z;

    // one block so the O-merge buffer can overlay the whole tile space
    __shared__ __align__(16) u16 sm[(64 + 64 + 128) * TS];   // 36.9 KB
    u16* Ks  = sm;                  // [64 keys][64 feat]
    u16* Vts = sm + 64 * TS;        // [64 d][64 keys]
    u16* Ps  = sm + 128 * TS;       // [128 q][64 keys]

    // ---- Q fragments in registers (wave's 64 q-rows; same every kt) -------
    bf16x8 qa[4][2];
#pragma unroll
    for (int mt = 0; mt < 4; ++mt)
#pragma unroll
        for (int ks = 0; ks < 2; ++ks)
            qa[mt][ks] = *(const bf16x8*)(Qg +
                ((size_t)((b * S_LEN + q0 + qh * 64 + mt * 16 + r16) * NH + h)) * DK +
                ks * 32 + qd * 8);

    // ---- staging: 256 threads cover each 64x64 tile in 2 strips -----------
    const int srow = tid >> 3, sc = (tid & 7) << 3;
    const u16* vsrc = Vtg + (((size_t)(b * NH + h)) * DK) * S_LEN;   // [d][s]
    u16x8 kreg[2], vreg[2];
#pragma unroll
    for (int it = 0; it < 2; ++it) {
        const int row = srow + it * 32;
        kreg[it] = *(const u16x8*)(Kg + ((size_t)((b * S_LEN + row) * NH + h)) * DK + sc);
        vreg[it] = *(const u16x8*)(vsrc + (size_t)row * S_LEN + sc);
    }

    float l_i[4] = {0.0f, 0.0f, 0.0f, 0.0f};
    f32x4 Oacc[4][4] = {};

    for (int kt = 0; kt < S_LEN / 64; ++kt) {
        const int ks0 = kt * 64;

        // ---- commit prefetched K/Vt tiles to LDS --------------------------
#pragma unroll
        for (int it = 0; it < 2; ++it) {
            const int row = srow + it * 32;
            *(u16x8*)&Ks[row * TS + sc]  = kreg[it];
            *(u16x8*)&Vts[row * TS + sc] = vreg[it];
        }

        // ---- pre-scaled mask, this wave's 32 keys (key = kh*32+nt*16+qd*4+rr)
        float4 mrow[2];
#pragma unroll
        for (int nt = 0; nt < 2; ++nt) {
            const float4 mm = ((const float4*)(maskg + (size_t)b * S_LEN + ks0))[kh * 8 + nt * 4 + qd];
            mrow[nt].x = mm.x * MSCALE; mrow[nt].y = mm.y * MSCALE;
            mrow[nt].z = mm.z * MSCALE; mrow[nt].w = mm.w * MSCALE;
        }
        __syncthreads();

        // ---- S^T = K @ Q^T + mask (mask as acc init); keys kh*32..+31 -----
        f32x4 sa[4][2];
#pragma unroll
        for (int mt = 0; mt < 4; ++mt)
#pragma unroll
            for (int nt = 0; nt < 2; ++nt) {
                sa[mt][nt][0] = mrow[nt].x; sa[mt][nt][1] = mrow[nt].y;
                sa[mt][nt][2] = mrow[nt].z; sa[mt][nt][3] = mrow[nt].w;
            }
#pragma unroll
        for (int ks = 0; ks < 2; ++ks) {
            bf16x8 kb[2];
#pragma unroll
            for (int nt = 0; nt < 2; ++nt)
                kb[nt] = *(const bf16x8*)&Ks[(kh * 32 + nt * 16 + r16) * TS + ks * 32 + qd * 8];
            __builtin_amdgcn_s_setprio(1);
#pragma unroll
            for (int mt = 0; mt < 4; ++mt)
#pragma unroll
                for (int nt = 0; nt < 2; ++nt)
                    sa[mt][nt] = __builtin_amdgcn_mfma_f32_16x16x32_bf16(kb[nt], qa[mt][ks], sa[mt][nt], 0, 0, 0);
            __builtin_amdgcn_s_setprio(0);
        }

        // ---- max-free softmax partial: p = exp2(s), l += sum (32 keys) ----
#pragma unroll
        for (int mt = 0; mt < 4; ++mt) {
            float rsum = 0.0f;
#pragma unroll
            for (int nt = 0; nt < 2; ++nt) {
                sa[mt][nt][0] = __builtin_amdgcn_exp2f(sa[mt][nt][0]);
                sa[mt][nt][1] = __builtin_amdgcn_exp2f(sa[mt][nt][1]);
                sa[mt][nt][2] = __builtin_amdgcn_exp2f(sa[mt][nt][2]);
                sa[mt][nt][3] = __builtin_amdgcn_exp2f(sa[mt][nt][3]);
                rsum += sa[mt][nt][0] + sa[mt][nt][1] + sa[mt][nt][2] + sa[mt][nt][3];
            }
            rsum += __shfl_xor(rsum, 16);
            rsum += __shfl_xor(rsum, 32);
            l_i[mt] += rsum;   // uniform across qd for fixed r16 (q = mt*16+r16)
        }

        // ---- P -> Ps [q][key], wave-private 64x32 block -------------------
#pragma unroll
        for (int mt = 0; mt < 4; ++mt)
#pragma unroll
            for (int nt = 0; nt < 2; ++nt) {
                __bf16 pk[4];
#pragma unroll
                for (int rr = 0; rr < 4; ++rr) pk[rr] = (__bf16)sa[mt][nt][rr];
                *(bf16x4*)&Ps[(qh * 64 + mt * 16 + r16) * TS + kh * 32 + nt * 16 + qd * 4] = *(bf16x4*)pk;
            }

        // ---- issue next tile's global loads (sa dead; caps VGPR peak) -----
        if (kt + 1 < S_LEN / 64) {
            const int ns0 = ks0 + 64;
#pragma unroll
            for (int it = 0; it < 2; ++it) {
                const int row = srow + it * 32;
                kreg[it] = *(const u16x8*)(Kg + ((size_t)((b * S_LEN + ns0 + row) * NH + h)) * DK + sc);
                vreg[it] = *(const u16x8*)(vsrc + (size_t)row * S_LEN + ns0 + sc);
            }
        }

        // ---- O += P @ V over this wave's 32 keys --------------------------
        {
            bf16x8 pa[4], vb[4];
#pragma unroll
            for (int mt = 0; mt < 4; ++mt)
                pa[mt] = *(const bf16x8*)&Ps[(qh * 64 + mt * 16 + r16) * TS + kh * 32 + qd * 8];
#pragma unroll
            for (int vt = 0; vt < 4; ++vt)
                vb[vt] = *(const bf16x8*)&Vts[(vt * 16 + r16) * TS + kh * 32 + qd * 8];
            __builtin_amdgcn_s_setprio(1);
#pragma unroll
            for (int mt = 0; mt < 4; ++mt)
#pragma unroll
                for (int vt = 0; vt < 4; ++vt)
                    Oacc[mt][vt] = __builtin_amdgcn_mfma_f32_16x16x32_bf16(pa[mt], vb[vt], Oacc[mt][vt], 0, 0, 0);
            __builtin_amdgcn_s_setprio(0);
        }
        __syncthreads();   // all waves done with Ks/Vts/Ps before next commit
    }

    // ---- merge kh partials (addition; max-free softmax) -------------------
    __syncthreads();                       // tile space dead, safe to overlay
    float* mb  = (float*)sm;               // [128 q][64 d] fp32 = 32 KB
    float* lsm = mb + 128 * 64;            // [2 qh][4 mt][16 r16] = 512 B
    if (kh == 0) {
#pragma unroll
        for (int mt = 0; mt < 4; ++mt) {
            if (qd == 0) lsm[(qh * 4 + mt) * 16 + r16] = l_i[mt];
#pragma unroll
            for (int vt = 0; vt < 4; ++vt)
#pragma unroll
                for (int rr = 0; rr < 4; ++rr)
                    mb[(qh * 64 + mt * 16 + qd * 4 + rr) * 64 + vt * 16 + r16] = Oacc[mt][vt][rr];
        }
    }
    __syncthreads();
    if (kh == 1) {
#pragma unroll
        for (int mt = 0; mt < 4; ++mt) {
            const float linv = 1.0f / (l_i[mt] + lsm[(qh * 4 + mt) * 16 + r16]);
#pragma unroll
            for (int rr = 0; rr < 4; ++rr) {
                const float lr = __shfl(linv, qd * 4 + rr);
                const int qrow = q0 + qh * 64 + mt * 16 + qd * 4 + rr;
#pragma unroll
                for (int vt = 0; vt < 4; ++vt) {
                    const float o = Oacc[mt][vt][rr] +
                        mb[(qh * 64 + mt * 16 + qd * 4 + rr) * 64 + vt * 16 + r16];
                    st_bf(&Og[((size_t)((b * S_LEN + qrow) * NH + h)) * DK + vt * 16 + r16],
                          o * lr);
                }
            }
        }
    }
}

// ---------------------------------------------------------------------------
// Residual + LayerNorm over D=768, one WAVE per row (4 rows/block).
// u16x4 vectorized loads (lane*4 + j*256), wave-local shfl reduce (no LDS,
// no barrier), bf16x4 / float4 stores, float4 gamma/beta.
// ---------------------------------------------------------------------------
__global__ __launch_bounds__(256, 4)
void resln_k(const u16* __restrict__ xb, const u16* __restrict__ yb,
             const float* __restrict__ gamma, const float* __restrict__ beta,
             u16* __restrict__ outb, float* __restrict__ outf) {
    const int lane = threadIdx.x & 63, wv = threadIdx.x >> 6;
    const int row = blockIdx.x * 4 + wv;
    const size_t base = (size_t)row * D_MODEL;
    float h[12];
    float s = 0.0f, s2 = 0.0f;
#pragma unroll
    for (int j = 0; j < 3; ++j) {
        const int c = lane * 4 + j * 256;
        const u16x4 xv = *(const u16x4*)(xb + base + c);
        const u16x4 yv = *(const u16x4*)(yb + base + c);
#pragma unroll
        for (int rr = 0; rr < 4; ++rr) {
            const float v = bf2f(xv[rr]) + bf2f(yv[rr]);
            h[j * 4 + rr] = v; s += v; s2 += v * v;
        }
    }
#pragma unroll
    for (int off = 32; off >= 1; off >>= 1) {
        s  += __shfl_xor(s, off);
        s2 += __shfl_xor(s2, off);
    }
    const float mu  = s * (1.0f / D_MODEL);
    const float var = s2 * (1.0f / D_MODEL) - mu * mu;
    const float rstd = rsqrtf(var + 1e-3f);
#pragma unroll
    for (int j = 0; j < 3; ++j) {
        const int c = lane * 4 + j * 256;
        const float4 g4 = *(const float4*)(gamma + c);
        const float4 be4 = *(const float4*)(beta + c);
        const float gg[4] = {g4.x, g4.y, g4.z, g4.w};
        const float bb[4] = {be4.x, be4.y, be4.z, be4.w};
        float o[4];
#pragma unroll
        for (int rr = 0; rr < 4; ++rr)
            o[rr] = (h[j * 4 + rr] - mu) * rstd * gg[rr] + bb[rr];
        if (outb) {
            __bf16 pk[4];
#pragma unroll
            for (int rr = 0; rr < 4; ++rr) pk[rr] = (__bf16)o[rr];
            *(bf16x4*)(outb + base + c) = *(bf16x4*)pk;
        }
        if (outf) {
            float4 ov = {o[0], o[1], o[2], o[3]};
            *(float4*)(outf + base + c) = ov;
        }
    }
}

// ---------------------------------------------------------------------------
extern "C" void kernel_launch(void* const* d_in, const int* in_sizes, int n_in,
                              void* d_out, int out_size, void* d_ws, size_t ws_size,
                              hipStream_t stream) {
    (void)in_sizes; (void)n_in; (void)out_size; (void)ws_size;
    const float* x    = (const float*)d_in[0];
    const float* mask = (const float*)d_in[1];
    const float* Wq = (const float*)d_in[2];  const float* bq  = (const float*)d_in[3];
    const float* Wk = (const float*)d_in[4];  const float* bk  = (const float*)d_in[5];
    const float* Wv = (const float*)d_in[6];  const float* bv  = (const float*)d_in[7];
    const float* Wo = (const float*)d_in[8];  const float* bo  = (const float*)d_in[9];
    const float* W1 = (const float*)d_in[10]; const float* b1  = (const float*)d_in[11];
    const float* W2 = (const float*)d_in[12]; const float* b2  = (const float*)d_in[13];
    const float* g1 = (const float*)d_in[14]; const float* be1 = (const float*)d_in[15];
    const float* g2 = (const float*)d_in[16]; const float* be2 = (const float*)d_in[17];

    char* ws = (char*)d_ws;
    u16* xb     = (u16*)(ws + 0);            // 12,582,912
    u16* WqkvT  = (u16*)(ws + 12582912);     //  3,538,944
    u16* WoT    = (u16*)(ws + 16121856);     //  1,179,648
    u16* W1T    = (u16*)(ws + 17301504);     //  3,145,728
    u16* W2T    = (u16*)(ws + 20447232);     //  3,145,728
    u16* Qb     = (u16*)(ws + 23592960);     // 12,582,912
    u16* Kb     = (u16*)(ws + 36175872);     // 12,582,912
    u16* Vtg    = (u16*)(ws + 48758784);     // 12,582,912 [B,H,Dk,S]
    u16* Ab     = (u16*)(ws + 61341696);     // 12,582,912
    u16* Yb     = (u16*)(ws + 73924608);     // 12,582,912
    u16* X1b    = (u16*)(ws + 86507520);     // 12,582,912 (end ~99 MB)
    u16* H1b    = (u16*)(ws + 23592960);     // reuse Qb/Kb/Vtg (dead after attn)
    u16* Y2b    = (u16*)(ws + 73924608);     // reuse Yb (dead after LN1)

    const dim3 blk(256);

    // 0. fused prep: x->bf16 + all 6 weight transposes (one dispatch)
    prep_k<<<dim3(11520), blk, 0, stream>>>(x, Wq, Wk, Wv, Wo, W1, W2,
                                            xb, WqkvT, WoT, W1T, W2T);

    // 1. fused QKV projection (V written pre-transposed), 2-phase, 3/CU
    qkv_gemm_k<<<dim3(64, 18), blk, 0, stream>>>(xb, WqkvT, bq, bk, bv, Qb, Kb, Vtg);

    // 2. flash attention v9 (key-split waves + setprio)
    attn_k<<<dim3(16, NH, 4), blk, 0, stream>>>(Qb, Kb, Vtg, mask, Ab);

    // 3. output projection: 128^2 4-phase (384 blocks, 2/CU resident)
    g4p_k<<<dim3(64, 6), blk, 0, stream>>>(Ab, WoT, bo, Yb, D_MODEL, D_MODEL);

    // 4. LN1: x1 = LN(x + Y) -> bf16 (wave-per-row, grid 2048)
    resln_k<<<dim3(M_TOK / 4), blk, 0, stream>>>(xb, Yb, g1, be1, X1b, nullptr);

    // 5. FF1: H1 = relu(x1@W1 + b1), 256^2 4-phase (front-loaded stages)
    ff1_k<<<dim3(32, 8), dim3(512), 0, stream>>>(X1b, W1T, b1, H1b);

    // 6. FF2: 128^2 4-phase (384 blocks, NT=32)
    g4p_k<<<dim3(64, 6), blk, 0, stream>>>(H1b, W2T, b2, Y2b, D_MODEL, D_FF);

    // 7. LN2: out = LN(x1 + Y2) fp32 -> d_out (wave-per-row, grid 2048)
    resln_k<<<dim3(M_TOK / 4), blk, 0, stream>>>(X1b, Y2b, g2, be2, nullptr, (float*)d_out);
}